// Round 9
// baseline (627.476 us; speedup 1.0000x reference)
//
#include <hip/hip_runtime.h>

#define N_NODES 50000
#define N_EDGES 800000
#define IN_F 96
#define H_F 256
#define N_NIE 4
#define SCAN_NB 196   // ceil(50000/256)
#define LDN 264       // ns_lds stride in shorts (33 x 16B -> conflict-free b128 reads)

typedef float f32x4 __attribute__((ext_vector_type(4)));
typedef short s16x8 __attribute__((ext_vector_type(8)));
typedef unsigned short u16x4 __attribute__((ext_vector_type(4)));
typedef unsigned short ushort;

__device__ __forceinline__ ushort bf16_rne(float f) {
    unsigned u = __float_as_uint(f);
    u += 0x7fffu + ((u >> 16) & 1u);
    return (ushort)(u >> 16);
}
__device__ __forceinline__ float bf16_f(ushort h) {
    return __uint_as_float(((unsigned)h) << 16);
}

// ---------------- CSR build ----------------
__global__ __launch_bounds__(256) void k_count(const int* __restrict__ rows,
                                               const int* __restrict__ cols,
                                               int* __restrict__ cnt) {
    int i = blockIdx.x * 256 + threadIdx.x;
    if (i >= N_EDGES / 2) return;
    int2 r2 = ((const int2*)rows)[i];
    int2 c2 = ((const int2*)cols)[i];
    if (r2.x != c2.x) atomicAdd(&cnt[r2.x], 1);
    if (r2.y != c2.y) atomicAdd(&cnt[r2.y], 1);
}

__global__ __launch_bounds__(256) void k_scan1(const int* __restrict__ cnt,
                                               int* __restrict__ rowptr,
                                               int* __restrict__ bsum) {
    __shared__ int s[256];
    int t = threadIdx.x, e = blockIdx.x * 256 + t;
    int v = (e < N_NODES) ? cnt[e] : 0;
    s[t] = v;
    __syncthreads();
    #pragma unroll
    for (int off = 1; off < 256; off <<= 1) {
        int nv = (t >= off) ? s[t - off] : 0;
        __syncthreads();
        s[t] += nv;
        __syncthreads();
    }
    if (e < N_NODES) rowptr[e] = s[t] - v;
    if (t == 255) bsum[blockIdx.x] = s[255];
}

__global__ __launch_bounds__(256) void k_scan2(int* __restrict__ bsum,
                                               int* __restrict__ boff,
                                               int* __restrict__ rowptr) {
    __shared__ int s[256];
    int t = threadIdx.x;
    int v = (t < SCAN_NB) ? bsum[t] : 0;
    s[t] = v;
    __syncthreads();
    #pragma unroll
    for (int off = 1; off < 256; off <<= 1) {
        int nv = (t >= off) ? s[t - off] : 0;
        __syncthreads();
        s[t] += nv;
        __syncthreads();
    }
    if (t < SCAN_NB) boff[t] = s[t] - v;
    if (t == 255) rowptr[N_NODES] = s[255];
}

__global__ __launch_bounds__(256) void k_scan3(const int* __restrict__ boff,
                                               const int* __restrict__ cnt,
                                               int* __restrict__ rowptr,
                                               int* __restrict__ cursor,
                                               float* __restrict__ dinv) {
    int e = blockIdx.x * 256 + threadIdx.x;
    if (e >= N_NODES) return;
    int r = rowptr[e] + boff[blockIdx.x];
    rowptr[e] = r;
    cursor[e] = r;
    dinv[e] = rsqrtf((float)cnt[e] + 1.0f);
}

// single-pass scatter; packs (col, dinv[col])
__global__ __launch_bounds__(256) void k_scatter(const int* __restrict__ rows,
                                                 const int* __restrict__ cols,
                                                 const float* __restrict__ dinv,
                                                 int* __restrict__ cursor,
                                                 int2* __restrict__ cw) {
    int e = blockIdx.x * 256 + threadIdx.x;
    if (e >= N_EDGES) return;
    int r = rows[e], c = cols[e];
    if (r == c) return;  // set_diag zeroes pre-existing diagonal entries
    int p = atomicAdd(&cursor[r], 1);
    cw[p] = make_int2(c, __float_as_int(dinv[c]));
}

// ---------------- weight transpose + split ----------------
__global__ __launch_bounds__(256) void k_wsplit(const float* __restrict__ src,
                                                ushort* __restrict__ dh,
                                                ushort* __restrict__ dl,
                                                int K, int N, int total) {
    int idx = blockIdx.x * 256 + threadIdx.x;
    if (idx >= total) return;
    int kn = K * N;
    int g = idx / kn, rem = idx - g * kn;
    int k = rem / N, n = rem - k * N;
    float v = src[idx];
    ushort h = bf16_rne(v);
    ushort l = bf16_rne(v - bf16_f(h));
    int dst = g * kn + n * K + k;
    dh[dst] = h;
    dl[dst] = l;
}

// ---------------- row-normalize features ----------------
__global__ __launch_bounds__(256) void k_norm(const float* __restrict__ feat,
                                              float* __restrict__ x) {
    int wid = (blockIdx.x * 256 + threadIdx.x) >> 6;
    int lane = threadIdx.x & 63;
    if (wid >= N_NODES) return;
    const float* fr = feat + (size_t)wid * IN_F;
    float v0 = (lane < IN_F) ? fr[lane] : 0.0f;
    float v1 = (lane < IN_F - 64) ? fr[64 + lane] : 0.0f;
    float ss = v0 * v0 + v1 * v1;
    #pragma unroll
    for (int o = 32; o; o >>= 1) ss += __shfl_xor(ss, o, 64);
    float inv = 1.0f / fmaxf(sqrtf(ss), 1e-12f);
    float* xr = x + (size_t)wid * IN_F;
    if (lane < IN_F) xr[lane] = v0 * inv;
    if (lane < IN_F - 64) xr[64 + lane] = v1 * inv;
}

// ---------------- CSR SpMM: 32-lane group/row, packed (c,w), unroll 2 ----------------
__global__ __launch_bounds__(256) void k_spmm_csr(const int* __restrict__ rowptr,
                                                  const int2* __restrict__ cw,
                                                  const float* __restrict__ dinv,
                                                  const float* __restrict__ x,
                                                  float* __restrict__ y) {
    int g = (blockIdx.x * 256 + threadIdx.x) >> 5;
    if (g >= N_NODES) return;
    int l = threadIdx.x & 31;  // lane handles feats l, l+32, l+64
    float dr = dinv[g];
    const float* xg = x + (size_t)g * IN_F;
    float s0 = xg[l], s1 = xg[l + 32], s2 = xg[l + 64];
    float a0 = 0.f, a1 = 0.f, a2 = 0.f;
    float b0 = 0.f, b1 = 0.f, b2 = 0.f;
    int k = rowptr[g], e = rowptr[g + 1];
    for (; k + 1 < e; k += 2) {
        int2 p0 = cw[k], p1 = cw[k + 1];
        float w0 = __int_as_float(p0.y), w1 = __int_as_float(p1.y);
        const float* x0 = x + (size_t)p0.x * IN_F;
        const float* x1 = x + (size_t)p1.x * IN_F;
        a0 += x0[l] * w0; a1 += x0[l + 32] * w0; a2 += x0[l + 64] * w0;
        b0 += x1[l] * w1; b1 += x1[l + 32] * w1; b2 += x1[l + 64] * w1;
    }
    if (k < e) {
        int2 p0 = cw[k];
        float w0 = __int_as_float(p0.y);
        const float* x0 = x + (size_t)p0.x * IN_F;
        a0 += x0[l] * w0; a1 += x0[l + 32] * w0; a2 += x0[l + 64] * w0;
    }
    float* yr = y + (size_t)g * IN_F;
    yr[l]      = dr * (a0 + b0 + dr * s0);
    yr[l + 32] = dr * (a1 + b1 + dr * s1);
    yr[l + 64] = dr * (a2 + b2 + dr * s2);
}

// ---------------- MEGA v2: only ns in LDS; A/B/W fragments direct global->reg ----------------
// out = relu( sum_i relu(h_i @ WsT_i + bs_i) @ WfT_i + bf ), written once.
// 66 KB LDS -> 2 blocks/CU; 2 barriers per hop (8 total).
__global__ __launch_bounds__(512, 4) void k_mega(const float* __restrict__ h0,
                                                 const float* __restrict__ h1,
                                                 const float* __restrict__ h2,
                                                 const float* __restrict__ h3,
                                                 const ushort* __restrict__ WsTh,
                                                 const ushort* __restrict__ WsTl,
                                                 const float* __restrict__ bs,
                                                 const ushort* __restrict__ WfTh,
                                                 const ushort* __restrict__ WfTl,
                                                 const float* __restrict__ bf,
                                                 float* __restrict__ out) {
    __shared__ ushort nsH[64 * LDN], nsL[64 * LDN];  // 66 KB total

    int m0 = blockIdx.x * 64;
    int tid = threadIdx.x;
    int lane = tid & 63, w = tid >> 6;
    int rsel = lane & 15, ksel = (lane >> 4) * 8;
    int crow = (lane >> 4) * 4, ccol = lane & 15;
    int rf = w & 3, cfb = (w >> 2) * 32;  // phase-1: wave computes ns rows rf*16..+15, cols {nc*64+cfb..+31}
    int cw0 = w * 32;                      // phase-2: wave owns out cols cw0..cw0+31

    f32x4 acc[4][2] = {};  // persistent: 64 rows x 32 cols per wave

    for (int hop = 0; hop < N_NIE; ++hop) {
        const float* A = (hop == 0) ? h0 : (hop == 1) ? h1 : (hop == 2) ? h2 : h3;
        const ushort* wsh = WsTh + hop * IN_F * H_F;  // [n=256][k=96]
        const ushort* wsl = WsTl + hop * IN_F * H_F;
        const float* bsi = bs + hop * H_F;

        // A fragments: direct fp32 load -> split bf16 registers, reused across 4 nc chunks
        int arow = m0 + rf * 16 + rsel;
        s16x8 Afh[3], Afl[3];
        #pragma unroll
        for (int ks = 0; ks < 3; ++ks) {
            int k0 = ks * 32 + ksel;
            float4 v0 = make_float4(0.f, 0.f, 0.f, 0.f), v1 = v0;
            if (arow < N_NODES) {
                v0 = *(const float4*)&A[(size_t)arow * IN_F + k0];
                v1 = *(const float4*)&A[(size_t)arow * IN_F + k0 + 4];
            }
            float vv[8] = {v0.x, v0.y, v0.z, v0.w, v1.x, v1.y, v1.z, v1.w};
            s16x8 hh, ll;
            #pragma unroll
            for (int q = 0; q < 8; ++q) {
                ushort h = bf16_rne(vv[q]);
                hh[q] = (short)h;
                ll[q] = (short)bf16_rne(vv[q] - bf16_f(h));
            }
            Afh[ks] = hh;
            Afl[ks] = ll;
        }
        // ---- phase 1: ns[64][256] = relu(A @ WsT + bs) -> LDS (B direct from global) ----
        #pragma unroll
        for (int nc = 0; nc < 4; ++nc) {
            f32x4 ac[2] = {};
            #pragma unroll
            for (int ks = 0; ks < 3; ++ks) {
                int k0 = ks * 32 + ksel;
                #pragma unroll
                for (int cf = 0; cf < 2; ++cf) {
                    int n = nc * 64 + cfb + cf * 16 + rsel;
                    s16x8 bh = *(const s16x8*)&wsh[(size_t)n * IN_F + k0];
                    s16x8 bl = *(const s16x8*)&wsl[(size_t)n * IN_F + k0];
                    ac[cf] = __builtin_amdgcn_mfma_f32_16x16x32_bf16(Afh[ks], bh, ac[cf], 0, 0, 0);
                    ac[cf] = __builtin_amdgcn_mfma_f32_16x16x32_bf16(Afh[ks], bl, ac[cf], 0, 0, 0);
                    ac[cf] = __builtin_amdgcn_mfma_f32_16x16x32_bf16(Afl[ks], bh, ac[cf], 0, 0, 0);
                }
            }
            #pragma unroll
            for (int cf = 0; cf < 2; ++cf) {
                int col = nc * 64 + cfb + cf * 16 + ccol;
                float bb = bsi[col];
                #pragma unroll
                for (int ii = 0; ii < 4; ++ii) {
                    int row = rf * 16 + crow + ii;
                    float v = fmaxf(ac[cf][ii] + bb, 0.f);
                    ushort h = bf16_rne(v);
                    nsH[row * LDN + col] = h;
                    nsL[row * LDN + col] = bf16_rne(v - bf16_f(h));
                }
            }
        }
        __syncthreads();  // ns tile complete
        // ---- phase 2: acc += ns @ WfT_hop (W direct from global, L2-resident) ----
        const ushort* wfh = WfTh + hop * H_F * H_F;  // [n=256][k=256]
        const ushort* wfl = WfTl + hop * H_F * H_F;
        #pragma unroll
        for (int kc = 0; kc < 8; ++kc) {
            int k0 = kc * 32 + ksel;
            s16x8 ah4[4], al4[4];
            #pragma unroll
            for (int mf = 0; mf < 4; ++mf) {
                ah4[mf] = *(const s16x8*)&nsH[(mf * 16 + rsel) * LDN + k0];
                al4[mf] = *(const s16x8*)&nsL[(mf * 16 + rsel) * LDN + k0];
            }
            #pragma unroll
            for (int cf = 0; cf < 2; ++cf) {
                int n = cw0 + cf * 16 + rsel;
                s16x8 bh = *(const s16x8*)&wfh[(size_t)n * H_F + k0];
                s16x8 bl = *(const s16x8*)&wfl[(size_t)n * H_F + k0];
                #pragma unroll
                for (int mf = 0; mf < 4; ++mf) {
                    acc[mf][cf] = __builtin_amdgcn_mfma_f32_16x16x32_bf16(ah4[mf], bh, acc[mf][cf], 0, 0, 0);
                    acc[mf][cf] = __builtin_amdgcn_mfma_f32_16x16x32_bf16(ah4[mf], bl, acc[mf][cf], 0, 0, 0);
                    acc[mf][cf] = __builtin_amdgcn_mfma_f32_16x16x32_bf16(al4[mf], bh, acc[mf][cf], 0, 0, 0);
                }
            }
        }
        __syncthreads();  // ns consumed; safe to overwrite next hop
    }
    // ---- final: out = relu(acc + bf), written once ----
    #pragma unroll
    for (int cf = 0; cf < 2; ++cf) {
        int col = cw0 + cf * 16 + ccol;
        float bb = bf[col];
        #pragma unroll
        for (int mf = 0; mf < 4; ++mf)
            #pragma unroll
            for (int ii = 0; ii < 4; ++ii) {
                int gm = m0 + mf * 16 + crow + ii;
                if (gm < N_NODES)
                    out[(size_t)gm * H_F + col] = fmaxf(acc[mf][cf][ii] + bb, 0.f);
            }
    }
}

extern "C" void kernel_launch(void* const* d_in, const int* in_sizes, int n_in,
                              void* d_out, int out_size, void* d_ws, size_t ws_size,
                              hipStream_t stream) {
    const int* ei = (const int*)d_in[0];
    const int* rows = ei;
    const int* cols = ei + N_EDGES;
    const float* feat = (const float*)d_in[1];
    const float* Ws = (const float*)d_in[2];
    const float* bs = (const float*)d_in[3];
    const float* Wf = (const float*)d_in[4];
    const float* bf = (const float*)d_in[5];
    float* out = (float*)d_out;

    // workspace layout (~85 MB)
    float* h0 = (float*)d_ws;                      // 4 x 4,800,000 f32
    float* h1 = h0 + (size_t)N_NODES * IN_F;
    float* h2 = h1 + (size_t)N_NODES * IN_F;
    float* h3 = h2 + (size_t)N_NODES * IN_F;
    ushort* WsTh = (ushort*)(h3 + (size_t)N_NODES * IN_F);  // 98,304 u16
    ushort* WsTl = WsTh + N_NIE * IN_F * H_F;
    ushort* WfTh = WsTl + N_NIE * IN_F * H_F;               // 262,144 u16
    ushort* WfTl = WfTh + N_NIE * H_F * H_F;
    float* dinv = (float*)(WfTl + N_NIE * H_F * H_F);       // 50,000 f32
    int* rowptr = (int*)(dinv + N_NODES);                   // 50,004 i32
    int* bsum = rowptr + 50004;                             // 256 i32
    int* boff = bsum + 256;                                 // 256 i32
    int2* cw = (int2*)(boff + 256);                         // 800,000 int2
    // CSR-build temporaries aliased into h1 (h1 written only later, by spmm)
    int* cnt = (int*)h1;
    int* cursor = cnt + N_NODES;

    hipMemsetAsync(cnt, 0, N_NODES * sizeof(int), stream);
    k_count<<<(N_EDGES / 2 + 255) / 256, 256, 0, stream>>>(rows, cols, cnt);
    k_scan1<<<SCAN_NB, 256, 0, stream>>>(cnt, rowptr, bsum);
    k_scan2<<<1, 256, 0, stream>>>(bsum, boff, rowptr);
    k_scan3<<<SCAN_NB, 256, 0, stream>>>(boff, cnt, rowptr, cursor, dinv);
    k_scatter<<<(N_EDGES + 255) / 256, 256, 0, stream>>>(rows, cols, dinv, cursor, cw);
    k_wsplit<<<(N_NIE * IN_F * H_F + 255) / 256, 256, 0, stream>>>(Ws, WsTh, WsTl, IN_F, H_F,
                                                                   N_NIE * IN_F * H_F);
    k_wsplit<<<(N_NIE * H_F * H_F + 255) / 256, 256, 0, stream>>>(Wf, WfTh, WfTl, H_F, H_F,
                                                                  N_NIE * H_F * H_F);
    k_norm<<<(N_NODES + 3) / 4, 256, 0, stream>>>(feat, h0);

    // hop chain first (h1..h3), then one fused GEMM pass
    k_spmm_csr<<<(N_NODES * 32 + 255) / 256, 256, 0, stream>>>(rowptr, cw, dinv, h0, h1);
    k_spmm_csr<<<(N_NODES * 32 + 255) / 256, 256, 0, stream>>>(rowptr, cw, dinv, h1, h2);
    k_spmm_csr<<<(N_NODES * 32 + 255) / 256, 256, 0, stream>>>(rowptr, cw, dinv, h2, h3);
    k_mega<<<(N_NODES + 63) / 64, 512, 0, stream>>>(h0, h1, h2, h3, WsTh, WsTl, bs,
                                                    WfTh, WfTl, bf, out);
}

// Round 10
// 579.865 us; speedup vs baseline: 1.0821x; 1.0821x over previous
//
#include <hip/hip_runtime.h>

#define N_NODES 50000
#define N_EDGES 800000
#define IN_F 96
#define H_F 256
#define N_NIE 4
#define SCAN_NB 196   // ceil(50000/256)
#define BM 48         // mega rows per block
#define NBLK 1042     // ceil(50000/48)
#define LDN 264       // ns stride (shorts): 528B rows -> 2-way max on b128 reads
#define LDB 104       // phase-1 B-stage stride (shorts)
#define LDW 36        // phase-2 W-stage stride (shorts): 16 distinct start banks

typedef float f32x4 __attribute__((ext_vector_type(4)));
typedef short s16x8 __attribute__((ext_vector_type(8)));
typedef unsigned short ushort;

__device__ __forceinline__ ushort bf16_rne(float f) {
    unsigned u = __float_as_uint(f);
    u += 0x7fffu + ((u >> 16) & 1u);
    return (ushort)(u >> 16);
}
__device__ __forceinline__ float bf16_f(ushort h) {
    return __uint_as_float(((unsigned)h) << 16);
}

// ---------------- CSR build ----------------
__global__ __launch_bounds__(256) void k_count(const int* __restrict__ rows,
                                               const int* __restrict__ cols,
                                               int* __restrict__ cnt) {
    int i = blockIdx.x * 256 + threadIdx.x;
    if (i >= N_EDGES / 2) return;
    int2 r2 = ((const int2*)rows)[i];
    int2 c2 = ((const int2*)cols)[i];
    if (r2.x != c2.x) atomicAdd(&cnt[r2.x], 1);
    if (r2.y != c2.y) atomicAdd(&cnt[r2.y], 1);
}

__global__ __launch_bounds__(256) void k_scan1(const int* __restrict__ cnt,
                                               int* __restrict__ rowptr,
                                               int* __restrict__ bsum) {
    __shared__ int s[256];
    int t = threadIdx.x, e = blockIdx.x * 256 + t;
    int v = (e < N_NODES) ? cnt[e] : 0;
    s[t] = v;
    __syncthreads();
    #pragma unroll
    for (int off = 1; off < 256; off <<= 1) {
        int nv = (t >= off) ? s[t - off] : 0;
        __syncthreads();
        s[t] += nv;
        __syncthreads();
    }
    if (e < N_NODES) rowptr[e] = s[t] - v;
    if (t == 255) bsum[blockIdx.x] = s[255];
}

__global__ __launch_bounds__(256) void k_scan2(int* __restrict__ bsum,
                                               int* __restrict__ boff,
                                               int* __restrict__ rowptr) {
    __shared__ int s[256];
    int t = threadIdx.x;
    int v = (t < SCAN_NB) ? bsum[t] : 0;
    s[t] = v;
    __syncthreads();
    #pragma unroll
    for (int off = 1; off < 256; off <<= 1) {
        int nv = (t >= off) ? s[t - off] : 0;
        __syncthreads();
        s[t] += nv;
        __syncthreads();
    }
    if (t < SCAN_NB) boff[t] = s[t] - v;
    if (t == 255) rowptr[N_NODES] = s[255];
}

__global__ __launch_bounds__(256) void k_scan3(const int* __restrict__ boff,
                                               const int* __restrict__ cnt,
                                               int* __restrict__ rowptr,
                                               int* __restrict__ cursor,
                                               float* __restrict__ dinv) {
    int e = blockIdx.x * 256 + threadIdx.x;
    if (e >= N_NODES) return;
    int r = rowptr[e] + boff[blockIdx.x];
    rowptr[e] = r;
    cursor[e] = r;
    dinv[e] = rsqrtf((float)cnt[e] + 1.0f);
}

// single-pass scatter; packs (col, dinv[col])
__global__ __launch_bounds__(256) void k_scatter(const int* __restrict__ rows,
                                                 const int* __restrict__ cols,
                                                 const float* __restrict__ dinv,
                                                 int* __restrict__ cursor,
                                                 int2* __restrict__ cw) {
    int e = blockIdx.x * 256 + threadIdx.x;
    if (e >= N_EDGES) return;
    int r = rows[e], c = cols[e];
    if (r == c) return;  // set_diag zeroes pre-existing diagonal entries
    int p = atomicAdd(&cursor[r], 1);
    cw[p] = make_int2(c, __float_as_int(dinv[c]));
}

// ---------------- weight transpose + bf16 round (hi only) ----------------
__global__ __launch_bounds__(256) void k_wsplit(const float* __restrict__ src,
                                                ushort* __restrict__ dh,
                                                int K, int N, int total) {
    int idx = blockIdx.x * 256 + threadIdx.x;
    if (idx >= total) return;
    int kn = K * N;
    int g = idx / kn, rem = idx - g * kn;
    int k = rem / N, n = rem - k * N;
    dh[g * kn + n * K + k] = bf16_rne(src[idx]);
}

// ---------------- row-normalize features ----------------
__global__ __launch_bounds__(256) void k_norm(const float* __restrict__ feat,
                                              float* __restrict__ x) {
    int wid = (blockIdx.x * 256 + threadIdx.x) >> 6;
    int lane = threadIdx.x & 63;
    if (wid >= N_NODES) return;
    const float* fr = feat + (size_t)wid * IN_F;
    float v0 = (lane < IN_F) ? fr[lane] : 0.0f;
    float v1 = (lane < IN_F - 64) ? fr[64 + lane] : 0.0f;
    float ss = v0 * v0 + v1 * v1;
    #pragma unroll
    for (int o = 32; o; o >>= 1) ss += __shfl_xor(ss, o, 64);
    float inv = 1.0f / fmaxf(sqrtf(ss), 1e-12f);
    float* xr = x + (size_t)wid * IN_F;
    if (lane < IN_F) xr[lane] = v0 * inv;
    if (lane < IN_F - 64) xr[64 + lane] = v1 * inv;
}

// ---------------- CSR SpMM: 32-lane group/row, packed (c,w), unroll 2 ----------------
__global__ __launch_bounds__(256) void k_spmm_csr(const int* __restrict__ rowptr,
                                                  const int2* __restrict__ cw,
                                                  const float* __restrict__ dinv,
                                                  const float* __restrict__ x,
                                                  float* __restrict__ y) {
    int g = (blockIdx.x * 256 + threadIdx.x) >> 5;
    if (g >= N_NODES) return;
    int l = threadIdx.x & 31;  // lane handles feats l, l+32, l+64
    float dr = dinv[g];
    const float* xg = x + (size_t)g * IN_F;
    float s0 = xg[l], s1 = xg[l + 32], s2 = xg[l + 64];
    float a0 = 0.f, a1 = 0.f, a2 = 0.f;
    float b0 = 0.f, b1 = 0.f, b2 = 0.f;
    int k = rowptr[g], e = rowptr[g + 1];
    for (; k + 1 < e; k += 2) {
        int2 p0 = cw[k], p1 = cw[k + 1];
        float w0 = __int_as_float(p0.y), w1 = __int_as_float(p1.y);
        const float* x0 = x + (size_t)p0.x * IN_F;
        const float* x1 = x + (size_t)p1.x * IN_F;
        a0 += x0[l] * w0; a1 += x0[l + 32] * w0; a2 += x0[l + 64] * w0;
        b0 += x1[l] * w1; b1 += x1[l + 32] * w1; b2 += x1[l + 64] * w1;
    }
    if (k < e) {
        int2 p0 = cw[k];
        float w0 = __int_as_float(p0.y);
        const float* x0 = x + (size_t)p0.x * IN_F;
        a0 += x0[l] * w0; a1 += x0[l + 32] * w0; a2 += x0[l + 64] * w0;
    }
    float* yr = y + (size_t)g * IN_F;
    yr[l]      = dr * (a0 + b0 + dr * s0);
    yr[l + 32] = dr * (a1 + b1 + dr * s1);
    yr[l + 64] = dr * (a2 + b2 + dr * s2);
}

// ---------------- MEGA v3: BM=48, ns split in LDS, weights bf16-hi staged, A direct ----------------
// out = relu( sum_i relu(h_i @ WsT_i + bs_i) @ WfT_i + bf ), written once.
// LDS 75.5 KB -> 2 blocks/CU. 20 barriers/hop.
__global__ __launch_bounds__(512, 4) void k_mega(const float* __restrict__ h0,
                                                 const float* __restrict__ h1,
                                                 const float* __restrict__ h2,
                                                 const float* __restrict__ h3,
                                                 const ushort* __restrict__ WsT,
                                                 const float* __restrict__ bs,
                                                 const ushort* __restrict__ WfT,
                                                 const float* __restrict__ bf,
                                                 float* __restrict__ out) {
    __shared__ ushort nsH[BM * LDN], nsL[BM * LDN];  // 50.7 KB
    __shared__ ushort U[128 * LDB];                  // 26 KB union: Bs [128][LDB] / Wst [256][LDW]
    ushort* Bs = U;
    ushort* Wst = U;

    int m0 = blockIdx.x * BM;
    int tid = threadIdx.x;
    int lane = tid & 63, w = tid >> 6;
    int rsel = lane & 15, ksel = (lane >> 4) * 8;
    int crow = (lane >> 4) * 4, ccol = lane & 15;

    f32x4 acc[3][2] = {};  // persistent: 48 rows x 32 cols per wave (cols w*32..+31)

    for (int hop = 0; hop < N_NIE; ++hop) {
        const float* A = (hop == 0) ? h0 : (hop == 1) ? h1 : (hop == 2) ? h2 : h3;
        const ushort* wsT = WsT + hop * IN_F * H_F;  // [n=256][k=96] bf16
        const float* bsi = bs + hop * H_F;

        // ---- phase 1: ns[48][256] = relu(A @ WsT + bs), 2 chunks of 128 cols ----
        #pragma unroll
        for (int c = 0; c < 2; ++c) {
            // stage B chunk: 128 rows (out-cols) x 96 k
            #pragma unroll
            for (int p = 0; p < 3; ++p) {
                int flat = tid + p * 512;  // 1536 short8 items
                int r = flat / 12, j = flat - r * 12;
                *(s16x8*)&Bs[r * LDB + j * 8] =
                    *(const s16x8*)&wsT[(size_t)(c * 128 + r) * IN_F + j * 8];
            }
            __syncthreads();
            #pragma unroll
            for (int rf = 0; rf < 3; ++rf) {
                int arow = m0 + rf * 16 + rsel;
                f32x4 ac = {};
                #pragma unroll
                for (int ks = 0; ks < 3; ++ks) {
                    int k0 = ks * 32 + ksel;
                    float4 v0 = make_float4(0.f, 0.f, 0.f, 0.f), v1 = v0;
                    if (arow < N_NODES) {
                        v0 = *(const float4*)&A[(size_t)arow * IN_F + k0];
                        v1 = *(const float4*)&A[(size_t)arow * IN_F + k0 + 4];
                    }
                    float vv[8] = {v0.x, v0.y, v0.z, v0.w, v1.x, v1.y, v1.z, v1.w};
                    s16x8 ah, al;
                    #pragma unroll
                    for (int q = 0; q < 8; ++q) {
                        ushort hq = bf16_rne(vv[q]);
                        ah[q] = (short)hq;
                        al[q] = (short)bf16_rne(vv[q] - bf16_f(hq));
                    }
                    s16x8 bh = *(const s16x8*)&Bs[(w * 16 + rsel) * LDB + k0];
                    ac = __builtin_amdgcn_mfma_f32_16x16x32_bf16(ah, bh, ac, 0, 0, 0);
                    ac = __builtin_amdgcn_mfma_f32_16x16x32_bf16(al, bh, ac, 0, 0, 0);
                }
                int col = c * 128 + w * 16 + ccol;
                float bb = bsi[col];
                #pragma unroll
                for (int ii = 0; ii < 4; ++ii) {
                    int row = rf * 16 + crow + ii;
                    float v = fmaxf(ac[ii] + bb, 0.f);
                    ushort hq = bf16_rne(v);
                    nsH[row * LDN + col] = hq;
                    nsL[row * LDN + col] = bf16_rne(v - bf16_f(hq));
                }
            }
            __syncthreads();
        }
        // ---- phase 2: acc += ns @ WfT_hop, 8 chunks of 32 k ----
        const ushort* wfT = WfT + hop * H_F * H_F;  // [n=256][k=256] bf16
        #pragma unroll
        for (int kc = 0; kc < 8; ++kc) {
            #pragma unroll
            for (int p = 0; p < 2; ++p) {
                int flat = tid + p * 512;  // 1024 short8 items
                int r = flat >> 2, j = flat & 3;
                *(s16x8*)&Wst[r * LDW + j * 8] =
                    *(const s16x8*)&wfT[(size_t)r * H_F + kc * 32 + j * 8];
            }
            __syncthreads();
            int k0 = kc * 32 + ksel;
            s16x8 ah4[3], al4[3];
            #pragma unroll
            for (int rf = 0; rf < 3; ++rf) {
                ah4[rf] = *(const s16x8*)&nsH[(rf * 16 + rsel) * LDN + k0];
                al4[rf] = *(const s16x8*)&nsL[(rf * 16 + rsel) * LDN + k0];
            }
            #pragma unroll
            for (int cf = 0; cf < 2; ++cf) {
                int n = w * 32 + cf * 16 + rsel;
                s16x8 bh = *(const s16x8*)&Wst[n * LDW + ksel];
                #pragma unroll
                for (int rf = 0; rf < 3; ++rf) {
                    acc[rf][cf] = __builtin_amdgcn_mfma_f32_16x16x32_bf16(ah4[rf], bh, acc[rf][cf], 0, 0, 0);
                    acc[rf][cf] = __builtin_amdgcn_mfma_f32_16x16x32_bf16(al4[rf], bh, acc[rf][cf], 0, 0, 0);
                }
            }
            __syncthreads();
        }
    }
    // ---- final: out = relu(acc + bf), written once ----
    #pragma unroll
    for (int cf = 0; cf < 2; ++cf) {
        int col = w * 32 + cf * 16 + ccol;
        float bb = bf[col];
        #pragma unroll
        for (int rf = 0; rf < 3; ++rf)
            #pragma unroll
            for (int ii = 0; ii < 4; ++ii) {
                int gm = m0 + rf * 16 + crow + ii;
                if (gm < N_NODES)
                    out[(size_t)gm * H_F + col] = fmaxf(acc[rf][cf][ii] + bb, 0.f);
            }
    }
}

extern "C" void kernel_launch(void* const* d_in, const int* in_sizes, int n_in,
                              void* d_out, int out_size, void* d_ws, size_t ws_size,
                              hipStream_t stream) {
    const int* ei = (const int*)d_in[0];
    const int* rows = ei;
    const int* cols = ei + N_EDGES;
    const float* feat = (const float*)d_in[1];
    const float* Ws = (const float*)d_in[2];
    const float* bs = (const float*)d_in[3];
    const float* Wf = (const float*)d_in[4];
    const float* bf = (const float*)d_in[5];
    float* out = (float*)d_out;

    // workspace layout (~84 MB)
    float* h0 = (float*)d_ws;                      // 4 x 4,800,000 f32
    float* h1 = h0 + (size_t)N_NODES * IN_F;
    float* h2 = h1 + (size_t)N_NODES * IN_F;
    float* h3 = h2 + (size_t)N_NODES * IN_F;
    ushort* WsT = (ushort*)(h3 + (size_t)N_NODES * IN_F);  // 98,304 u16
    ushort* WfT = WsT + N_NIE * IN_F * H_F;                // 262,144 u16
    float* dinv = (float*)(WfT + N_NIE * H_F * H_F);       // 50,000 f32
    int* rowptr = (int*)(dinv + N_NODES);                  // 50,004 i32
    int* bsum = rowptr + 50004;                            // 256 i32
    int* boff = bsum + 256;                                // 256 i32
    int2* cw = (int2*)(boff + 256);                        // 800,000 int2
    // CSR-build temporaries aliased into h1 (h1 written only later, by spmm)
    int* cnt = (int*)h1;
    int* cursor = cnt + N_NODES;

    hipMemsetAsync(cnt, 0, N_NODES * sizeof(int), stream);
    k_count<<<(N_EDGES / 2 + 255) / 256, 256, 0, stream>>>(rows, cols, cnt);
    k_scan1<<<SCAN_NB, 256, 0, stream>>>(cnt, rowptr, bsum);
    k_scan2<<<1, 256, 0, stream>>>(bsum, boff, rowptr);
    k_scan3<<<SCAN_NB, 256, 0, stream>>>(boff, cnt, rowptr, cursor, dinv);
    k_scatter<<<(N_EDGES + 255) / 256, 256, 0, stream>>>(rows, cols, dinv, cursor, cw);
    k_wsplit<<<(N_NIE * IN_F * H_F + 255) / 256, 256, 0, stream>>>(Ws, WsT, IN_F, H_F,
                                                                   N_NIE * IN_F * H_F);
    k_wsplit<<<(N_NIE * H_F * H_F + 255) / 256, 256, 0, stream>>>(Wf, WfT, H_F, H_F,
                                                                  N_NIE * H_F * H_F);
    k_norm<<<(N_NODES + 3) / 4, 256, 0, stream>>>(feat, h0);

    // hop chain first (h1..h3), then one fused GEMM pass
    k_spmm_csr<<<(N_NODES * 32 + 255) / 256, 256, 0, stream>>>(rowptr, cw, dinv, h0, h1);
    k_spmm_csr<<<(N_NODES * 32 + 255) / 256, 256, 0, stream>>>(rowptr, cw, dinv, h1, h2);
    k_spmm_csr<<<(N_NODES * 32 + 255) / 256, 256, 0, stream>>>(rowptr, cw, dinv, h2, h3);
    k_mega<<<NBLK, 512, 0, stream>>>(h0, h1, h2, h3, WsT, bs, WfT, bf, out);
}

// Round 11
// 524.144 us; speedup vs baseline: 1.1971x; 1.1063x over previous
//
#include <hip/hip_runtime.h>

#define N_NODES 50000
#define N_EDGES 800000
#define IN_F 96
#define H_F 256
#define N_NIE 4
#define SCAN_NB 196   // ceil(50000/256)
#define BM 32         // mega rows per block
#define NBLK 1563     // ceil(50000/32)
#define LDN 264       // ns stride (shorts): 528B rows, 16B-aligned, 2-way max
#define LDB 104       // phase-1 B-stage stride (shorts), 208B aligned
#define LDW 40        // phase-2 W-stage stride (shorts): 80B rows, 16B-aligned

typedef float f32x4 __attribute__((ext_vector_type(4)));
typedef short s16x8 __attribute__((ext_vector_type(8)));
typedef unsigned short ushort;

__device__ __forceinline__ ushort bf16_rne(float f) {
    unsigned u = __float_as_uint(f);
    u += 0x7fffu + ((u >> 16) & 1u);
    return (ushort)(u >> 16);
}
__device__ __forceinline__ float bf16_f(ushort h) {
    return __uint_as_float(((unsigned)h) << 16);
}

// ---------------- CSR build ----------------
__global__ __launch_bounds__(256) void k_count(const int* __restrict__ rows,
                                               const int* __restrict__ cols,
                                               int* __restrict__ cnt) {
    int i = blockIdx.x * 256 + threadIdx.x;
    if (i >= N_EDGES / 2) return;
    int2 r2 = ((const int2*)rows)[i];
    int2 c2 = ((const int2*)cols)[i];
    if (r2.x != c2.x) atomicAdd(&cnt[r2.x], 1);
    if (r2.y != c2.y) atomicAdd(&cnt[r2.y], 1);
}

__global__ __launch_bounds__(256) void k_scan1(const int* __restrict__ cnt,
                                               int* __restrict__ rowptr,
                                               int* __restrict__ bsum) {
    __shared__ int s[256];
    int t = threadIdx.x, e = blockIdx.x * 256 + t;
    int v = (e < N_NODES) ? cnt[e] : 0;
    s[t] = v;
    __syncthreads();
    #pragma unroll
    for (int off = 1; off < 256; off <<= 1) {
        int nv = (t >= off) ? s[t - off] : 0;
        __syncthreads();
        s[t] += nv;
        __syncthreads();
    }
    if (e < N_NODES) rowptr[e] = s[t] - v;
    if (t == 255) bsum[blockIdx.x] = s[255];
}

__global__ __launch_bounds__(256) void k_scan2(int* __restrict__ bsum,
                                               int* __restrict__ boff,
                                               int* __restrict__ rowptr) {
    __shared__ int s[256];
    int t = threadIdx.x;
    int v = (t < SCAN_NB) ? bsum[t] : 0;
    s[t] = v;
    __syncthreads();
    #pragma unroll
    for (int off = 1; off < 256; off <<= 1) {
        int nv = (t >= off) ? s[t - off] : 0;
        __syncthreads();
        s[t] += nv;
        __syncthreads();
    }
    if (t < SCAN_NB) boff[t] = s[t] - v;
    if (t == 255) rowptr[N_NODES] = s[255];
}

__global__ __launch_bounds__(256) void k_scan3(const int* __restrict__ boff,
                                               const int* __restrict__ cnt,
                                               int* __restrict__ rowptr,
                                               int* __restrict__ cursor,
                                               float* __restrict__ dinv) {
    int e = blockIdx.x * 256 + threadIdx.x;
    if (e >= N_NODES) return;
    int r = rowptr[e] + boff[blockIdx.x];
    rowptr[e] = r;
    cursor[e] = r;
    dinv[e] = rsqrtf((float)cnt[e] + 1.0f);
}

// single-pass scatter; packs (col, dinv[col])
__global__ __launch_bounds__(256) void k_scatter(const int* __restrict__ rows,
                                                 const int* __restrict__ cols,
                                                 const float* __restrict__ dinv,
                                                 int* __restrict__ cursor,
                                                 int2* __restrict__ cw) {
    int e = blockIdx.x * 256 + threadIdx.x;
    if (e >= N_EDGES) return;
    int r = rows[e], c = cols[e];
    if (r == c) return;  // set_diag zeroes pre-existing diagonal entries
    int p = atomicAdd(&cursor[r], 1);
    cw[p] = make_int2(c, __float_as_int(dinv[c]));
}

// ---------------- weight transpose + bf16 round (hi only) ----------------
__global__ __launch_bounds__(256) void k_wsplit(const float* __restrict__ src,
                                                ushort* __restrict__ dh,
                                                int K, int N, int total) {
    int idx = blockIdx.x * 256 + threadIdx.x;
    if (idx >= total) return;
    int kn = K * N;
    int g = idx / kn, rem = idx - g * kn;
    int k = rem / N, n = rem - k * N;
    dh[g * kn + n * K + k] = bf16_rne(src[idx]);
}

// ---------------- row-normalize features ----------------
__global__ __launch_bounds__(256) void k_norm(const float* __restrict__ feat,
                                              float* __restrict__ x) {
    int wid = (blockIdx.x * 256 + threadIdx.x) >> 6;
    int lane = threadIdx.x & 63;
    if (wid >= N_NODES) return;
    const float* fr = feat + (size_t)wid * IN_F;
    float v0 = (lane < IN_F) ? fr[lane] : 0.0f;
    float v1 = (lane < IN_F - 64) ? fr[64 + lane] : 0.0f;
    float ss = v0 * v0 + v1 * v1;
    #pragma unroll
    for (int o = 32; o; o >>= 1) ss += __shfl_xor(ss, o, 64);
    float inv = 1.0f / fmaxf(sqrtf(ss), 1e-12f);
    float* xr = x + (size_t)wid * IN_F;
    if (lane < IN_F) xr[lane] = v0 * inv;
    if (lane < IN_F - 64) xr[64 + lane] = v1 * inv;
}

// ---------------- CSR SpMM: 32-lane group/row, packed (c,w), unroll 2 ----------------
__global__ __launch_bounds__(256) void k_spmm_csr(const int* __restrict__ rowptr,
                                                  const int2* __restrict__ cw,
                                                  const float* __restrict__ dinv,
                                                  const float* __restrict__ x,
                                                  float* __restrict__ y) {
    int g = (blockIdx.x * 256 + threadIdx.x) >> 5;
    if (g >= N_NODES) return;
    int l = threadIdx.x & 31;  // lane handles feats l, l+32, l+64
    float dr = dinv[g];
    const float* xg = x + (size_t)g * IN_F;
    float s0 = xg[l], s1 = xg[l + 32], s2 = xg[l + 64];
    float a0 = 0.f, a1 = 0.f, a2 = 0.f;
    float b0 = 0.f, b1 = 0.f, b2 = 0.f;
    int k = rowptr[g], e = rowptr[g + 1];
    for (; k + 1 < e; k += 2) {
        int2 p0 = cw[k], p1 = cw[k + 1];
        float w0 = __int_as_float(p0.y), w1 = __int_as_float(p1.y);
        const float* x0 = x + (size_t)p0.x * IN_F;
        const float* x1 = x + (size_t)p1.x * IN_F;
        a0 += x0[l] * w0; a1 += x0[l + 32] * w0; a2 += x0[l + 64] * w0;
        b0 += x1[l] * w1; b1 += x1[l + 32] * w1; b2 += x1[l + 64] * w1;
    }
    if (k < e) {
        int2 p0 = cw[k];
        float w0 = __int_as_float(p0.y);
        const float* x0 = x + (size_t)p0.x * IN_F;
        a0 += x0[l] * w0; a1 += x0[l + 32] * w0; a2 += x0[l + 64] * w0;
    }
    float* yr = y + (size_t)g * IN_F;
    yr[l]      = dr * (a0 + b0 + dr * s0);
    yr[l + 32] = dr * (a1 + b1 + dr * s1);
    yr[l + 64] = dr * (a2 + b2 + dr * s2);
}

// ---------------- MEGA v4: BM=32, hoisted A-conv, T14 dbuf Wf staging ----------------
// out = relu( sum_i relu(h_i @ WsT_i + bs_i) @ WfT_i + bf ), written once.
// LDS 74.7 KB -> 2 blocks/CU. 13 barriers/hop, W-staging overlapped with MFMA.
__global__ __launch_bounds__(512, 4) void k_mega(const float* __restrict__ h0,
                                                 const float* __restrict__ h1,
                                                 const float* __restrict__ h2,
                                                 const float* __restrict__ h3,
                                                 const ushort* __restrict__ WsT,
                                                 const float* __restrict__ bs,
                                                 const ushort* __restrict__ WfT,
                                                 const float* __restrict__ bf,
                                                 float* __restrict__ out) {
    __shared__ ushort nsH[BM * LDN], nsL[BM * LDN];  // 33.8 KB
    __shared__ ushort U[2 * 256 * LDW];              // 40.9 KB: Wst dbuf / Bs overlay
    ushort* Bs = U;  // [128][LDB] = 13312 shorts, fits in U

    int m0 = blockIdx.x * BM;
    int tid = threadIdx.x;
    int lane = tid & 63, w = tid >> 6;
    int rsel = lane & 15, ksel = (lane >> 4) * 8;
    int crow = (lane >> 4) * 4, ccol = lane & 15;

    f32x4 acc[2][2] = {};  // persistent: rows rf*16.., cols w*32+cf*16..

    for (int hop = 0; hop < N_NIE; ++hop) {
        const float* A = (hop == 0) ? h0 : (hop == 1) ? h1 : (hop == 2) ? h2 : h3;
        const ushort* wsT = WsT + hop * IN_F * H_F;  // [n=256][k=96] bf16
        const ushort* wfT = WfT + hop * H_F * H_F;   // [n=256][k=256] bf16
        const float* bsi = bs + hop * H_F;

        // ---- hoisted: A rows -> split bf16 fragments, once per hop ----
        s16x8 Afh[2][3], Afl[2][3];
        #pragma unroll
        for (int rf = 0; rf < 2; ++rf) {
            int arow = m0 + rf * 16 + rsel;
            #pragma unroll
            for (int ks = 0; ks < 3; ++ks) {
                int k0 = ks * 32 + ksel;
                float4 v0 = make_float4(0.f, 0.f, 0.f, 0.f), v1 = v0;
                if (arow < N_NODES) {
                    v0 = *(const float4*)&A[(size_t)arow * IN_F + k0];
                    v1 = *(const float4*)&A[(size_t)arow * IN_F + k0 + 4];
                }
                float vv[8] = {v0.x, v0.y, v0.z, v0.w, v1.x, v1.y, v1.z, v1.w};
                s16x8 ah, al;
                #pragma unroll
                for (int q = 0; q < 8; ++q) {
                    ushort hq = bf16_rne(vv[q]);
                    ah[q] = (short)hq;
                    al[q] = (short)bf16_rne(vv[q] - bf16_f(hq));
                }
                Afh[rf][ks] = ah;
                Afl[rf][ks] = al;
            }
        }
        // ---- phase 1: ns[32][256] = relu(A @ WsT + bs), 2 chunks of 128 cols ----
        #pragma unroll
        for (int c = 0; c < 2; ++c) {
            __syncthreads();  // union region free / previous reads done
            #pragma unroll
            for (int p = 0; p < 3; ++p) {
                int flat = tid + p * 512;  // 1536 short8 items: [128][12]
                int r = flat / 12, j = flat - r * 12;
                *(s16x8*)&Bs[r * LDB + j * 8] =
                    *(const s16x8*)&wsT[(size_t)(c * 128 + r) * IN_F + j * 8];
            }
            __syncthreads();
            #pragma unroll
            for (int rf = 0; rf < 2; ++rf) {
                f32x4 ac = {};
                #pragma unroll
                for (int ks = 0; ks < 3; ++ks) {
                    s16x8 bh = *(const s16x8*)&Bs[(w * 16 + rsel) * LDB + ks * 32 + ksel];
                    ac = __builtin_amdgcn_mfma_f32_16x16x32_bf16(Afh[rf][ks], bh, ac, 0, 0, 0);
                    ac = __builtin_amdgcn_mfma_f32_16x16x32_bf16(Afl[rf][ks], bh, ac, 0, 0, 0);
                }
                int col = c * 128 + w * 16 + ccol;
                float bb = bsi[col];
                #pragma unroll
                for (int ii = 0; ii < 4; ++ii) {
                    int row = rf * 16 + crow + ii;
                    float v = fmaxf(ac[ii] + bb, 0.f);
                    ushort hq = bf16_rne(v);
                    nsH[row * LDN + col] = hq;
                    nsL[row * LDN + col] = bf16_rne(v - bf16_f(hq));
                }
            }
        }
        // ---- phase 2: acc += ns @ WfT, dbuf Wst, 1 barrier per kc (T14) ----
        s16x8 wreg[2];
        #pragma unroll
        for (int p = 0; p < 2; ++p) {  // preload kc=0 (in flight across the bar)
            int flat = tid + p * 512;
            int r = flat >> 2, j = flat & 3;
            wreg[p] = *(const s16x8*)&wfT[(size_t)r * H_F + j * 8];
        }
        __syncthreads();  // ns complete; Bs reads done -> union free for Wst
        int cur = 0;
        #pragma unroll
        for (int kc = 0; kc < 8; ++kc) {
            ushort* Wcur = U + cur * 256 * LDW;
            #pragma unroll
            for (int p = 0; p < 2; ++p) {
                int flat = tid + p * 512;
                int r = flat >> 2, j = flat & 3;
                *(s16x8*)&Wcur[r * LDW + j * 8] = wreg[p];
            }
            __syncthreads();  // Wcur visible; prior compute reads ordered by arrival
            if (kc < 7) {
                #pragma unroll
                for (int p = 0; p < 2; ++p) {  // issue next chunk loads under MFMA
                    int flat = tid + p * 512;
                    int r = flat >> 2, j = flat & 3;
                    wreg[p] = *(const s16x8*)&wfT[(size_t)r * H_F + (kc + 1) * 32 + j * 8];
                }
            }
            int k0 = kc * 32 + ksel;
            s16x8 ah[2], al[2];
            #pragma unroll
            for (int rf = 0; rf < 2; ++rf) {
                ah[rf] = *(const s16x8*)&nsH[(rf * 16 + rsel) * LDN + k0];
                al[rf] = *(const s16x8*)&nsL[(rf * 16 + rsel) * LDN + k0];
            }
            #pragma unroll
            for (int cf = 0; cf < 2; ++cf) {
                s16x8 bh = *(const s16x8*)&Wcur[(w * 32 + cf * 16 + rsel) * LDW + ksel];
                #pragma unroll
                for (int rf = 0; rf < 2; ++rf) {
                    acc[rf][cf] = __builtin_amdgcn_mfma_f32_16x16x32_bf16(ah[rf], bh, acc[rf][cf], 0, 0, 0);
                    acc[rf][cf] = __builtin_amdgcn_mfma_f32_16x16x32_bf16(al[rf], bh, acc[rf][cf], 0, 0, 0);
                }
            }
            cur ^= 1;
        }
    }
    // ---- final: out = relu(acc + bf), written once ----
    #pragma unroll
    for (int cf = 0; cf < 2; ++cf) {
        int col = w * 32 + cf * 16 + ccol;
        float bb = bf[col];
        #pragma unroll
        for (int rf = 0; rf < 2; ++rf)
            #pragma unroll
            for (int ii = 0; ii < 4; ++ii) {
                int gm = m0 + rf * 16 + crow + ii;
                if (gm < N_NODES)
                    out[(size_t)gm * H_F + col] = fmaxf(acc[rf][cf][ii] + bb, 0.f);
            }
    }
}

extern "C" void kernel_launch(void* const* d_in, const int* in_sizes, int n_in,
                              void* d_out, int out_size, void* d_ws, size_t ws_size,
                              hipStream_t stream) {
    const int* ei = (const int*)d_in[0];
    const int* rows = ei;
    const int* cols = ei + N_EDGES;
    const float* feat = (const float*)d_in[1];
    const float* Ws = (const float*)d_in[2];
    const float* bs = (const float*)d_in[3];
    const float* Wf = (const float*)d_in[4];
    const float* bf = (const float*)d_in[5];
    float* out = (float*)d_out;

    // workspace layout (~84 MB)
    float* h0 = (float*)d_ws;                      // 4 x 4,800,000 f32
    float* h1 = h0 + (size_t)N_NODES * IN_F;
    float* h2 = h1 + (size_t)N_NODES * IN_F;
    float* h3 = h2 + (size_t)N_NODES * IN_F;
    ushort* WsT = (ushort*)(h3 + (size_t)N_NODES * IN_F);  // 98,304 u16
    ushort* WfT = WsT + N_NIE * IN_F * H_F;                // 262,144 u16
    float* dinv = (float*)(WfT + N_NIE * H_F * H_F);       // 50,000 f32
    int* rowptr = (int*)(dinv + N_NODES);                  // 50,004 i32
    int* bsum = rowptr + 50004;                            // 256 i32
    int* boff = bsum + 256;                                // 256 i32
    int2* cw = (int2*)(boff + 256);                        // 800,000 int2
    // CSR-build temporaries aliased into h1 (h1 written only later, by spmm)
    int* cnt = (int*)h1;
    int* cursor = cnt + N_NODES;

    hipMemsetAsync(cnt, 0, N_NODES * sizeof(int), stream);
    k_count<<<(N_EDGES / 2 + 255) / 256, 256, 0, stream>>>(rows, cols, cnt);
    k_scan1<<<SCAN_NB, 256, 0, stream>>>(cnt, rowptr, bsum);
    k_scan2<<<1, 256, 0, stream>>>(bsum, boff, rowptr);
    k_scan3<<<SCAN_NB, 256, 0, stream>>>(boff, cnt, rowptr, cursor, dinv);
    k_scatter<<<(N_EDGES + 255) / 256, 256, 0, stream>>>(rows, cols, dinv, cursor, cw);
    k_wsplit<<<(N_NIE * IN_F * H_F + 255) / 256, 256, 0, stream>>>(Ws, WsT, IN_F, H_F,
                                                                   N_NIE * IN_F * H_F);
    k_wsplit<<<(N_NIE * H_F * H_F + 255) / 256, 256, 0, stream>>>(Wf, WfT, H_F, H_F,
                                                                  N_NIE * H_F * H_F);
    k_norm<<<(N_NODES + 3) / 4, 256, 0, stream>>>(feat, h0);

    // hop chain first (h1..h3), then one fused GEMM pass
    k_spmm_csr<<<(N_NODES * 32 + 255) / 256, 256, 0, stream>>>(rowptr, cw, dinv, h0, h1);
    k_spmm_csr<<<(N_NODES * 32 + 255) / 256, 256, 0, stream>>>(rowptr, cw, dinv, h1, h2);
    k_spmm_csr<<<(N_NODES * 32 + 255) / 256, 256, 0, stream>>>(rowptr, cw, dinv, h2, h3);
    k_mega<<<NBLK, 512, 0, stream>>>(h0, h1, h2, h3, WsT, bs, WfT, bf, out);
}

// Round 12
// 368.560 us; speedup vs baseline: 1.7025x; 1.4221x over previous
//
#include <hip/hip_runtime.h>

#define N_NODES 50000
#define N_EDGES 800000
#define IN_F 96
#define H_F 256
#define N_NIE 4
#define SCAN_NB 196   // ceil(50000/256)
#define BM 32         // mega rows per block
#define NBLK 1563     // ceil(50000/32)
#define LDN 264       // nsH stride (shorts): 528B rows, 16B-aligned
#define LDA1 104      // A-lds stride (shorts): 208B rows
#define LDB 104       // phase-1 B-stage stride (shorts)
#define LDW 40        // phase-2 W-stage stride (shorts): 80B rows, 16B-aligned

typedef float f32x4 __attribute__((ext_vector_type(4)));
typedef short s16x8 __attribute__((ext_vector_type(8)));
typedef unsigned short ushort;

__device__ __forceinline__ ushort bf16_rne(float f) {
    unsigned u = __float_as_uint(f);
    u += 0x7fffu + ((u >> 16) & 1u);
    return (ushort)(u >> 16);
}
__device__ __forceinline__ float bf16_f(ushort h) {
    return __uint_as_float(((unsigned)h) << 16);
}

// ---------------- CSR build ----------------
__global__ __launch_bounds__(256) void k_count(const int* __restrict__ rows,
                                               const int* __restrict__ cols,
                                               int* __restrict__ cnt) {
    int i = blockIdx.x * 256 + threadIdx.x;
    if (i >= N_EDGES / 2) return;
    int2 r2 = ((const int2*)rows)[i];
    int2 c2 = ((const int2*)cols)[i];
    if (r2.x != c2.x) atomicAdd(&cnt[r2.x], 1);
    if (r2.y != c2.y) atomicAdd(&cnt[r2.y], 1);
}

__global__ __launch_bounds__(256) void k_scan1(const int* __restrict__ cnt,
                                               int* __restrict__ rowptr,
                                               int* __restrict__ bsum) {
    __shared__ int s[256];
    int t = threadIdx.x, e = blockIdx.x * 256 + t;
    int v = (e < N_NODES) ? cnt[e] : 0;
    s[t] = v;
    __syncthreads();
    #pragma unroll
    for (int off = 1; off < 256; off <<= 1) {
        int nv = (t >= off) ? s[t - off] : 0;
        __syncthreads();
        s[t] += nv;
        __syncthreads();
    }
    if (e < N_NODES) rowptr[e] = s[t] - v;
    if (t == 255) bsum[blockIdx.x] = s[255];
}

__global__ __launch_bounds__(256) void k_scan2(int* __restrict__ bsum,
                                               int* __restrict__ boff,
                                               int* __restrict__ rowptr) {
    __shared__ int s[256];
    int t = threadIdx.x;
    int v = (t < SCAN_NB) ? bsum[t] : 0;
    s[t] = v;
    __syncthreads();
    #pragma unroll
    for (int off = 1; off < 256; off <<= 1) {
        int nv = (t >= off) ? s[t - off] : 0;
        __syncthreads();
        s[t] += nv;
        __syncthreads();
    }
    if (t < SCAN_NB) boff[t] = s[t] - v;
    if (t == 255) rowptr[N_NODES] = s[255];
}

__global__ __launch_bounds__(256) void k_scan3(const int* __restrict__ boff,
                                               const int* __restrict__ cnt,
                                               int* __restrict__ rowptr,
                                               int* __restrict__ cursor,
                                               float* __restrict__ dinv) {
    int e = blockIdx.x * 256 + threadIdx.x;
    if (e >= N_NODES) return;
    int r = rowptr[e] + boff[blockIdx.x];
    rowptr[e] = r;
    cursor[e] = r;
    dinv[e] = rsqrtf((float)cnt[e] + 1.0f);
}

// single-pass scatter; packs (col, dinv[col])
__global__ __launch_bounds__(256) void k_scatter(const int* __restrict__ rows,
                                                 const int* __restrict__ cols,
                                                 const float* __restrict__ dinv,
                                                 int* __restrict__ cursor,
                                                 int2* __restrict__ cw) {
    int e = blockIdx.x * 256 + threadIdx.x;
    if (e >= N_EDGES) return;
    int r = rows[e], c = cols[e];
    if (r == c) return;  // set_diag zeroes pre-existing diagonal entries
    int p = atomicAdd(&cursor[r], 1);
    cw[p] = make_int2(c, __float_as_int(dinv[c]));
}

// ---------------- weight transpose + bf16 round (hi only) ----------------
__global__ __launch_bounds__(256) void k_wsplit(const float* __restrict__ src,
                                                ushort* __restrict__ dh,
                                                int K, int N, int total) {
    int idx = blockIdx.x * 256 + threadIdx.x;
    if (idx >= total) return;
    int kn = K * N;
    int g = idx / kn, rem = idx - g * kn;
    int k = rem / N, n = rem - k * N;
    dh[g * kn + n * K + k] = bf16_rne(src[idx]);
}

// ---------------- row-normalize features ----------------
__global__ __launch_bounds__(256) void k_norm(const float* __restrict__ feat,
                                              float* __restrict__ x) {
    int wid = (blockIdx.x * 256 + threadIdx.x) >> 6;
    int lane = threadIdx.x & 63;
    if (wid >= N_NODES) return;
    const float* fr = feat + (size_t)wid * IN_F;
    float v0 = (lane < IN_F) ? fr[lane] : 0.0f;
    float v1 = (lane < IN_F - 64) ? fr[64 + lane] : 0.0f;
    float ss = v0 * v0 + v1 * v1;
    #pragma unroll
    for (int o = 32; o; o >>= 1) ss += __shfl_xor(ss, o, 64);
    float inv = 1.0f / fmaxf(sqrtf(ss), 1e-12f);
    float* xr = x + (size_t)wid * IN_F;
    if (lane < IN_F) xr[lane] = v0 * inv;
    if (lane < IN_F - 64) xr[64 + lane] = v1 * inv;
}

// ---------------- CSR SpMM: 32-lane group/row, packed (c,w), unroll 2 ----------------
__global__ __launch_bounds__(256) void k_spmm_csr(const int* __restrict__ rowptr,
                                                  const int2* __restrict__ cw,
                                                  const float* __restrict__ dinv,
                                                  const float* __restrict__ x,
                                                  float* __restrict__ y) {
    int g = (blockIdx.x * 256 + threadIdx.x) >> 5;
    if (g >= N_NODES) return;
    int l = threadIdx.x & 31;  // lane handles feats l, l+32, l+64
    float dr = dinv[g];
    const float* xg = x + (size_t)g * IN_F;
    float s0 = xg[l], s1 = xg[l + 32], s2 = xg[l + 64];
    float a0 = 0.f, a1 = 0.f, a2 = 0.f;
    float b0 = 0.f, b1 = 0.f, b2 = 0.f;
    int k = rowptr[g], e = rowptr[g + 1];
    for (; k + 1 < e; k += 2) {
        int2 p0 = cw[k], p1 = cw[k + 1];
        float w0 = __int_as_float(p0.y), w1 = __int_as_float(p1.y);
        const float* x0 = x + (size_t)p0.x * IN_F;
        const float* x1 = x + (size_t)p1.x * IN_F;
        a0 += x0[l] * w0; a1 += x0[l + 32] * w0; a2 += x0[l + 64] * w0;
        b0 += x1[l] * w1; b1 += x1[l + 32] * w1; b2 += x1[l + 64] * w1;
    }
    if (k < e) {
        int2 p0 = cw[k];
        float w0 = __int_as_float(p0.y);
        const float* x0 = x + (size_t)p0.x * IN_F;
        a0 += x0[l] * w0; a1 += x0[l + 32] * w0; a2 += x0[l + 64] * w0;
    }
    float* yr = y + (size_t)g * IN_F;
    yr[l]      = dr * (a0 + b0 + dr * s0);
    yr[l + 32] = dr * (a1 + b1 + dr * s1);
    yr[l + 64] = dr * (a2 + b2 + dr * s2);
}

// ---------------- MEGA v5: A-split in LDS (once/block), nsH only, T14 dbuf W ----------------
// out = relu( sum_i relu(h_i @ WsT_i + bs_i) @ WfT_i + bf ), written once.
// LDS 71 KB -> 2 blocks/CU; low reg pressure (no spill); 1 barrier/kc.
__global__ __launch_bounds__(512, 4) void k_mega(const float* __restrict__ h0,
                                                 const float* __restrict__ h1,
                                                 const float* __restrict__ h2,
                                                 const float* __restrict__ h3,
                                                 const ushort* __restrict__ WsT,
                                                 const float* __restrict__ bs,
                                                 const ushort* __restrict__ WfT,
                                                 const float* __restrict__ bf,
                                                 float* __restrict__ out) {
    __shared__ ushort nsH[BM * LDN];        // 16.9 KB
    __shared__ ushort Ah[BM * LDA1];        // 6.7 KB
    __shared__ ushort Al[BM * LDA1];        // 6.7 KB
    __shared__ ushort U[2 * 256 * LDW];     // 40.9 KB: W dbuf / Bs overlay
    ushort* Bs = U;  // [128][LDB] = 13312 shorts, fits

    int m0 = blockIdx.x * BM;
    int tid = threadIdx.x;
    int lane = tid & 63, w = tid >> 6;
    int rsel = lane & 15, ksel = (lane >> 4) * 8;
    int crow = (lane >> 4) * 4, ccol = lane & 15;

    f32x4 acc[2][2] = {};  // persistent: rows rf*16.., cols w*32+cf*16..

    for (int hop = 0; hop < N_NIE; ++hop) {
        const float* A = (hop == 0) ? h0 : (hop == 1) ? h1 : (hop == 2) ? h2 : h3;
        const ushort* wsT = WsT + hop * IN_F * H_F;  // [n=256][k=96] bf16
        const ushort* wfT = WfT + hop * H_F * H_F;   // [n=256][k=256] bf16
        const float* bsi = bs + hop * H_F;

        // ---- stage A (fp32 -> split bf16) to LDS, once per block ----
        if (tid < BM * 12) {  // 384 short8 items per array
            int r = tid / 12, j = tid - r * 12;
            int gm = m0 + r;
            float4 v0 = make_float4(0.f, 0.f, 0.f, 0.f), v1 = v0;
            if (gm < N_NODES) {
                v0 = *(const float4*)&A[(size_t)gm * IN_F + j * 8];
                v1 = *(const float4*)&A[(size_t)gm * IN_F + j * 8 + 4];
            }
            float vv[8] = {v0.x, v0.y, v0.z, v0.w, v1.x, v1.y, v1.z, v1.w};
            s16x8 ah, al;
            #pragma unroll
            for (int q = 0; q < 8; ++q) {
                ushort hq = bf16_rne(vv[q]);
                ah[q] = (short)hq;
                al[q] = (short)bf16_rne(vv[q] - bf16_f(hq));
            }
            *(s16x8*)&Ah[r * LDA1 + j * 8] = ah;
            *(s16x8*)&Al[r * LDA1 + j * 8] = al;
        }
        // ---- phase 1: nsH[32][256] = relu(A @ WsT + bs), 2 chunks of 128 cols ----
        #pragma unroll
        for (int c = 0; c < 2; ++c) {
            __syncthreads();  // U free (prev reads done); A-lds writes ordered (c=0)
            #pragma unroll
            for (int p = 0; p < 3; ++p) {
                int flat = tid + p * 512;  // 1536 short8 items: [128][12]
                int r = flat / 12, j = flat - r * 12;
                *(s16x8*)&Bs[r * LDB + j * 8] =
                    *(const s16x8*)&wsT[(size_t)(c * 128 + r) * IN_F + j * 8];
            }
            __syncthreads();  // Bs + A-lds visible
            #pragma unroll
            for (int rf = 0; rf < 2; ++rf) {
                f32x4 ac = {};
                #pragma unroll
                for (int ks = 0; ks < 3; ++ks) {
                    int k0 = ks * 32 + ksel;
                    s16x8 ah = *(const s16x8*)&Ah[(rf * 16 + rsel) * LDA1 + k0];
                    s16x8 al = *(const s16x8*)&Al[(rf * 16 + rsel) * LDA1 + k0];
                    s16x8 bh = *(const s16x8*)&Bs[(w * 16 + rsel) * LDB + k0];
                    ac = __builtin_amdgcn_mfma_f32_16x16x32_bf16(ah, bh, ac, 0, 0, 0);
                    ac = __builtin_amdgcn_mfma_f32_16x16x32_bf16(al, bh, ac, 0, 0, 0);
                }
                int col = c * 128 + w * 16 + ccol;
                float bb = bsi[col];
                #pragma unroll
                for (int ii = 0; ii < 4; ++ii) {
                    int row = rf * 16 + crow + ii;
                    nsH[row * LDN + col] = bf16_rne(fmaxf(ac[ii] + bb, 0.f));
                }
            }
        }
        // ---- phase 2: acc += ns @ WfT, dbuf W staging, 1 barrier per kc (T14) ----
        s16x8 wreg[2];
        #pragma unroll
        for (int p = 0; p < 2; ++p) {  // preload kc=0
            int flat = tid + p * 512;
            int r = flat >> 2, j = flat & 3;
            wreg[p] = *(const s16x8*)&wfT[(size_t)r * H_F + j * 8];
        }
        __syncthreads();  // nsH complete; Bs reads done -> U free for W dbuf
        int cur = 0;
        #pragma unroll
        for (int kc = 0; kc < 8; ++kc) {
            ushort* Wcur = U + cur * 256 * LDW;
            #pragma unroll
            for (int p = 0; p < 2; ++p) {
                int flat = tid + p * 512;
                int r = flat >> 2, j = flat & 3;
                *(s16x8*)&Wcur[r * LDW + j * 8] = wreg[p];
            }
            __syncthreads();  // Wcur visible (reads of other buf already done)
            if (kc < 7) {
                #pragma unroll
                for (int p = 0; p < 2; ++p) {  // issue next chunk under MFMA
                    int flat = tid + p * 512;
                    int r = flat >> 2, j = flat & 3;
                    wreg[p] = *(const s16x8*)&wfT[(size_t)r * H_F + (kc + 1) * 32 + j * 8];
                }
            }
            int k0 = kc * 32 + ksel;
            s16x8 ah[2];
            #pragma unroll
            for (int rf = 0; rf < 2; ++rf)
                ah[rf] = *(const s16x8*)&nsH[(rf * 16 + rsel) * LDN + k0];
            #pragma unroll
            for (int cf = 0; cf < 2; ++cf) {
                s16x8 bh = *(const s16x8*)&Wcur[(w * 32 + cf * 16 + rsel) * LDW + ksel];
                #pragma unroll
                for (int rf = 0; rf < 2; ++rf)
                    acc[rf][cf] = __builtin_amdgcn_mfma_f32_16x16x32_bf16(ah[rf], bh, acc[rf][cf], 0, 0, 0);
            }
            cur ^= 1;
        }
    }
    // ---- final: out = relu(acc + bf), written once ----
    #pragma unroll
    for (int cf = 0; cf < 2; ++cf) {
        int col = w * 32 + cf * 16 + ccol;
        float bb = bf[col];
        #pragma unroll
        for (int rf = 0; rf < 2; ++rf)
            #pragma unroll
            for (int ii = 0; ii < 4; ++ii) {
                int gm = m0 + rf * 16 + crow + ii;
                if (gm < N_NODES)
                    out[(size_t)gm * H_F + col] = fmaxf(acc[rf][cf][ii] + bb, 0.f);
            }
    }
}

extern "C" void kernel_launch(void* const* d_in, const int* in_sizes, int n_in,
                              void* d_out, int out_size, void* d_ws, size_t ws_size,
                              hipStream_t stream) {
    const int* ei = (const int*)d_in[0];
    const int* rows = ei;
    const int* cols = ei + N_EDGES;
    const float* feat = (const float*)d_in[1];
    const float* Ws = (const float*)d_in[2];
    const float* bs = (const float*)d_in[3];
    const float* Wf = (const float*)d_in[4];
    const float* bf = (const float*)d_in[5];
    float* out = (float*)d_out;

    // workspace layout (~84 MB)
    float* h0 = (float*)d_ws;                      // 4 x 4,800,000 f32
    float* h1 = h0 + (size_t)N_NODES * IN_F;
    float* h2 = h1 + (size_t)N_NODES * IN_F;
    float* h3 = h2 + (size_t)N_NODES * IN_F;
    ushort* WsT = (ushort*)(h3 + (size_t)N_NODES * IN_F);  // 98,304 u16
    ushort* WfT = WsT + N_NIE * IN_F * H_F;                // 262,144 u16
    float* dinv = (float*)(WfT + N_NIE * H_F * H_F);       // 50,000 f32
    int* rowptr = (int*)(dinv + N_NODES);                  // 50,004 i32
    int* bsum = rowptr + 50004;                            // 256 i32
    int* boff = bsum + 256;                                // 256 i32
    int2* cw = (int2*)(boff + 256);                        // 800,000 int2
    // CSR-build temporaries aliased into h1 (h1 written only later, by spmm)
    int* cnt = (int*)h1;
    int* cursor = cnt + N_NODES;

    hipMemsetAsync(cnt, 0, N_NODES * sizeof(int), stream);
    k_count<<<(N_EDGES / 2 + 255) / 256, 256, 0, stream>>>(rows, cols, cnt);
    k_scan1<<<SCAN_NB, 256, 0, stream>>>(cnt, rowptr, bsum);
    k_scan2<<<1, 256, 0, stream>>>(bsum, boff, rowptr);
    k_scan3<<<SCAN_NB, 256, 0, stream>>>(boff, cnt, rowptr, cursor, dinv);
    k_scatter<<<(N_EDGES + 255) / 256, 256, 0, stream>>>(rows, cols, dinv, cursor, cw);
    k_wsplit<<<(N_NIE * IN_F * H_F + 255) / 256, 256, 0, stream>>>(Ws, WsT, IN_F, H_F,
                                                                   N_NIE * IN_F * H_F);
    k_wsplit<<<(N_NIE * H_F * H_F + 255) / 256, 256, 0, stream>>>(Wf, WfT, H_F, H_F,
                                                                  N_NIE * H_F * H_F);
    k_norm<<<(N_NODES + 3) / 4, 256, 0, stream>>>(feat, h0);

    // hop chain first (h1..h3), then one fused GEMM pass
    k_spmm_csr<<<(N_NODES * 32 + 255) / 256, 256, 0, stream>>>(rowptr, cw, dinv, h0, h1);
    k_spmm_csr<<<(N_NODES * 32 + 255) / 256, 256, 0, stream>>>(rowptr, cw, dinv, h1, h2);
    k_spmm_csr<<<(N_NODES * 32 + 255) / 256, 256, 0, stream>>>(rowptr, cw, dinv, h2, h3);
    k_mega<<<NBLK, 512, 0, stream>>>(h0, h1, h2, h3, WsT, bs, WfT, bf, out);
}

// Round 13
// 360.628 us; speedup vs baseline: 1.7400x; 1.0220x over previous
//
#include <hip/hip_runtime.h>

#define N_NODES 50000
#define N_EDGES 800000
#define IN_F 96
#define H_F 256
#define N_NIE 4
#define SCAN_NB 196   // ceil(50000/256)
#define BM 64         // mega rows per block
#define NBLK 782      // ceil(50000/64)
#define LDA1 104      // A-lds / Bs stride (shorts): 208B rows
#define LDW 40        // W-stage stride (shorts): 80B rows, 16B-aligned

typedef float f32x4 __attribute__((ext_vector_type(4)));
typedef short s16x8 __attribute__((ext_vector_type(8)));
typedef unsigned short ushort;

__device__ __forceinline__ ushort bf16_rne(float f) {
    unsigned u = __float_as_uint(f);
    u += 0x7fffu + ((u >> 16) & 1u);
    return (ushort)(u >> 16);
}
__device__ __forceinline__ float bf16_f(ushort h) {
    return __uint_as_float(((unsigned)h) << 16);
}

// ---------------- CSR build ----------------
__global__ __launch_bounds__(256) void k_count(const int* __restrict__ rows,
                                               const int* __restrict__ cols,
                                               int* __restrict__ cnt) {
    int i = blockIdx.x * 256 + threadIdx.x;
    if (i >= N_EDGES / 2) return;
    int2 r2 = ((const int2*)rows)[i];
    int2 c2 = ((const int2*)cols)[i];
    if (r2.x != c2.x) atomicAdd(&cnt[r2.x], 1);
    if (r2.y != c2.y) atomicAdd(&cnt[r2.y], 1);
}

__global__ __launch_bounds__(256) void k_scan1(const int* __restrict__ cnt,
                                               int* __restrict__ rowptr,
                                               int* __restrict__ bsum) {
    __shared__ int s[256];
    int t = threadIdx.x, e = blockIdx.x * 256 + t;
    int v = (e < N_NODES) ? cnt[e] : 0;
    s[t] = v;
    __syncthreads();
    #pragma unroll
    for (int off = 1; off < 256; off <<= 1) {
        int nv = (t >= off) ? s[t - off] : 0;
        __syncthreads();
        s[t] += nv;
        __syncthreads();
    }
    if (e < N_NODES) rowptr[e] = s[t] - v;
    if (t == 255) bsum[blockIdx.x] = s[255];
}

__global__ __launch_bounds__(256) void k_scan2(int* __restrict__ bsum,
                                               int* __restrict__ boff,
                                               int* __restrict__ rowptr) {
    __shared__ int s[256];
    int t = threadIdx.x;
    int v = (t < SCAN_NB) ? bsum[t] : 0;
    s[t] = v;
    __syncthreads();
    #pragma unroll
    for (int off = 1; off < 256; off <<= 1) {
        int nv = (t >= off) ? s[t - off] : 0;
        __syncthreads();
        s[t] += nv;
        __syncthreads();
    }
    if (t < SCAN_NB) boff[t] = s[t] - v;
    if (t == 255) rowptr[N_NODES] = s[255];
}

__global__ __launch_bounds__(256) void k_scan3(const int* __restrict__ boff,
                                               const int* __restrict__ cnt,
                                               int* __restrict__ rowptr,
                                               int* __restrict__ cursor,
                                               float* __restrict__ dinv) {
    int e = blockIdx.x * 256 + threadIdx.x;
    if (e >= N_NODES) return;
    int r = rowptr[e] + boff[blockIdx.x];
    rowptr[e] = r;
    cursor[e] = r;
    dinv[e] = rsqrtf((float)cnt[e] + 1.0f);
}

// single-pass scatter; packs (col, dinv[col])
__global__ __launch_bounds__(256) void k_scatter(const int* __restrict__ rows,
                                                 const int* __restrict__ cols,
                                                 const float* __restrict__ dinv,
                                                 int* __restrict__ cursor,
                                                 int2* __restrict__ cw) {
    int e = blockIdx.x * 256 + threadIdx.x;
    if (e >= N_EDGES) return;
    int r = rows[e], c = cols[e];
    if (r == c) return;  // set_diag zeroes pre-existing diagonal entries
    int p = atomicAdd(&cursor[r], 1);
    cw[p] = make_int2(c, __float_as_int(dinv[c]));
}

// ---------------- weight transpose + bf16 round (hi only) ----------------
__global__ __launch_bounds__(256) void k_wsplit(const float* __restrict__ src,
                                                ushort* __restrict__ dh,
                                                int K, int N, int total) {
    int idx = blockIdx.x * 256 + threadIdx.x;
    if (idx >= total) return;
    int kn = K * N;
    int g = idx / kn, rem = idx - g * kn;
    int k = rem / N, n = rem - k * N;
    dh[g * kn + n * K + k] = bf16_rne(src[idx]);
}

// ---------------- row-normalize features ----------------
__global__ __launch_bounds__(256) void k_norm(const float* __restrict__ feat,
                                              float* __restrict__ x) {
    int wid = (blockIdx.x * 256 + threadIdx.x) >> 6;
    int lane = threadIdx.x & 63;
    if (wid >= N_NODES) return;
    const float* fr = feat + (size_t)wid * IN_F;
    float v0 = (lane < IN_F) ? fr[lane] : 0.0f;
    float v1 = (lane < IN_F - 64) ? fr[64 + lane] : 0.0f;
    float ss = v0 * v0 + v1 * v1;
    #pragma unroll
    for (int o = 32; o; o >>= 1) ss += __shfl_xor(ss, o, 64);
    float inv = 1.0f / fmaxf(sqrtf(ss), 1e-12f);
    float* xr = x + (size_t)wid * IN_F;
    if (lane < IN_F) xr[lane] = v0 * inv;
    if (lane < IN_F - 64) xr[64 + lane] = v1 * inv;
}

// ---------------- CSR SpMM: 32-lane group/row, packed (c,w), unroll 2 ----------------
__global__ __launch_bounds__(256) void k_spmm_csr(const int* __restrict__ rowptr,
                                                  const int2* __restrict__ cw,
                                                  const float* __restrict__ dinv,
                                                  const float* __restrict__ x,
                                                  float* __restrict__ y) {
    int g = (blockIdx.x * 256 + threadIdx.x) >> 5;
    if (g >= N_NODES) return;
    int l = threadIdx.x & 31;  // lane handles feats l, l+32, l+64
    float dr = dinv[g];
    const float* xg = x + (size_t)g * IN_F;
    float s0 = xg[l], s1 = xg[l + 32], s2 = xg[l + 64];
    float a0 = 0.f, a1 = 0.f, a2 = 0.f;
    float b0 = 0.f, b1 = 0.f, b2 = 0.f;
    int k = rowptr[g], e = rowptr[g + 1];
    for (; k + 1 < e; k += 2) {
        int2 p0 = cw[k], p1 = cw[k + 1];
        float w0 = __int_as_float(p0.y), w1 = __int_as_float(p1.y);
        const float* x0 = x + (size_t)p0.x * IN_F;
        const float* x1 = x + (size_t)p1.x * IN_F;
        a0 += x0[l] * w0; a1 += x0[l + 32] * w0; a2 += x0[l + 64] * w0;
        b0 += x1[l] * w1; b1 += x1[l + 32] * w1; b2 += x1[l + 64] * w1;
    }
    if (k < e) {
        int2 p0 = cw[k];
        float w0 = __int_as_float(p0.y);
        const float* x0 = x + (size_t)p0.x * IN_F;
        a0 += x0[l] * w0; a1 += x0[l + 32] * w0; a2 += x0[l + 64] * w0;
    }
    float* yr = y + (size_t)g * IN_F;
    yr[l]      = dr * (a0 + b0 + dr * s0);
    yr[l + 32] = dr * (a1 + b1 + dr * s1);
    yr[l + 64] = dr * (a2 + b2 + dr * s2);
}

// ---------------- MEGA v6: BM=64, swizzled nsH, W-dbuf aliased onto dead A region ----------------
// out = relu( sum_i relu(h_i @ WsT_i + bs_i) @ WfT_i + bf ), written once.
// LDS 79.9 KB -> 2 blocks/CU; 1 barrier/kc (dbuf); weight re-reads halved vs BM=32.
__global__ __launch_bounds__(512, 4) void k_mega(const float* __restrict__ h0,
                                                 const float* __restrict__ h1,
                                                 const float* __restrict__ h2,
                                                 const float* __restrict__ h3,
                                                 const ushort* __restrict__ WsT,
                                                 const float* __restrict__ bs,
                                                 const ushort* __restrict__ WfT,
                                                 const float* __restrict__ bf,
                                                 float* __restrict__ out) {
    __shared__ ushort SM[39936];        // 79.87 KB total
    ushort* nsH = SM;                   // [64][256] swizzled (16384 shorts)
    ushort* Ah  = SM + 16384;           // [64][LDA1] (6656)
    ushort* Al  = SM + 23040;           // [64][LDA1] (6656)
    ushort* U   = SM + 29696;           // 10240: Wbuf0 [256][LDW] / Bs [64][LDA1] overlay
    ushort* Wb0 = U;
    ushort* Wb1 = Ah;                   // aliases A region (dead during phase 2)

    int m0 = blockIdx.x * BM;
    int tid = threadIdx.x;
    int lane = tid & 63, w = tid >> 6;
    int rsel = lane & 15, g = lane >> 4, ksel = g * 8;
    int crow = g * 4, ccol = rsel;
    int rw0 = (w & 3) * 16;   // phase-1 row-fragment base
    int cwb = (w >> 2) * 32;  // phase-1 col base within each 64-col chunk

    f32x4 acc[4][2] = {};  // persistent: rows rf*16.., cols w*32+cf*16..

    for (int hop = 0; hop < N_NIE; ++hop) {
        const float* A = (hop == 0) ? h0 : (hop == 1) ? h1 : (hop == 2) ? h2 : h3;
        const ushort* wsT = WsT + hop * IN_F * H_F;  // [n=256][k=96] bf16
        const ushort* wfT = WfT + hop * H_F * H_F;   // [n=256][k=256] bf16
        const float* bsi = bs + hop * H_F;

        // ---- stage A (fp32 -> split bf16) to LDS, once per block (768 items) ----
        #pragma unroll
        for (int p = 0; p < 2; ++p) {
            int flat = tid + p * 512;
            if (flat < 768) {
                int r = flat / 12, j = flat - r * 12;
                int gm = m0 + r;
                float4 v0 = make_float4(0.f, 0.f, 0.f, 0.f), v1 = v0;
                if (gm < N_NODES) {
                    v0 = *(const float4*)&A[(size_t)gm * IN_F + j * 8];
                    v1 = *(const float4*)&A[(size_t)gm * IN_F + j * 8 + 4];
                }
                float vv[8] = {v0.x, v0.y, v0.z, v0.w, v1.x, v1.y, v1.z, v1.w};
                s16x8 ah, al;
                #pragma unroll
                for (int q = 0; q < 8; ++q) {
                    ushort hq = bf16_rne(vv[q]);
                    ah[q] = (short)hq;
                    al[q] = (short)bf16_rne(vv[q] - bf16_f(hq));
                }
                *(s16x8*)&Ah[r * LDA1 + j * 8] = ah;
                *(s16x8*)&Al[r * LDA1 + j * 8] = al;
            }
        }
        // ---- phase 1: nsH[64][256] = relu(A @ WsT + bs), 4 chunks of 64 cols ----
        #pragma unroll
        for (int c = 0; c < 4; ++c) {
            __syncthreads();  // U free (prev reads done); orders A-stage (c=0)
            #pragma unroll
            for (int p = 0; p < 2; ++p) {
                int flat = tid + p * 512;  // 768 items: [64][12]
                if (flat < 768) {
                    int r = flat / 12, j = flat - r * 12;
                    *(s16x8*)&U[r * LDA1 + j * 8] =
                        *(const s16x8*)&wsT[(size_t)(c * 64 + r) * IN_F + j * 8];
                }
            }
            __syncthreads();  // Bs + A-lds visible
            f32x4 ac[2] = {};
            #pragma unroll
            for (int ks = 0; ks < 3; ++ks) {
                int k0 = ks * 32 + ksel;
                s16x8 ah = *(const s16x8*)&Ah[(rw0 + rsel) * LDA1 + k0];
                s16x8 al = *(const s16x8*)&Al[(rw0 + rsel) * LDA1 + k0];
                s16x8 b0 = *(const s16x8*)&U[(cwb + rsel) * LDA1 + k0];
                s16x8 b1 = *(const s16x8*)&U[(cwb + 16 + rsel) * LDA1 + k0];
                ac[0] = __builtin_amdgcn_mfma_f32_16x16x32_bf16(ah, b0, ac[0], 0, 0, 0);
                ac[0] = __builtin_amdgcn_mfma_f32_16x16x32_bf16(al, b0, ac[0], 0, 0, 0);
                ac[1] = __builtin_amdgcn_mfma_f32_16x16x32_bf16(ah, b1, ac[1], 0, 0, 0);
                ac[1] = __builtin_amdgcn_mfma_f32_16x16x32_bf16(al, b1, ac[1], 0, 0, 0);
            }
            #pragma unroll
            for (int cf = 0; cf < 2; ++cf) {
                int col = c * 64 + cwb + cf * 16 + ccol;
                float bb = bsi[col];
                #pragma unroll
                for (int ii = 0; ii < 4; ++ii) {
                    int row = rw0 + crow + ii;
                    nsH[row * 256 + (col ^ ((row & 7) << 3))] =
                        bf16_rne(fmaxf(ac[cf][ii] + bb, 0.f));
                }
            }
        }
        // ---- phase 2: acc += ns @ WfT, dbuf W (buf1 aliases A region), 1 bar/kc ----
        s16x8 wreg[2];
        #pragma unroll
        for (int p = 0; p < 2; ++p) {  // preload kc=0
            int flat = tid + p * 512;
            int r = flat >> 2, j = flat & 3;
            wreg[p] = *(const s16x8*)&wfT[(size_t)r * H_F + j * 8];
        }
        __syncthreads();  // nsH complete; Bs/A reads drained -> U & A regions writable
        int cur = 0;
        #pragma unroll
        for (int kc = 0; kc < 8; ++kc) {
            ushort* Wcur = cur ? Wb1 : Wb0;
            #pragma unroll
            for (int p = 0; p < 2; ++p) {
                int flat = tid + p * 512;
                int r = flat >> 2, j = flat & 3;
                *(s16x8*)&Wcur[r * LDW + j * 8] = wreg[p];
            }
            __syncthreads();  // Wcur visible; other-buf reads already drained
            if (kc < 7) {
                #pragma unroll
                for (int p = 0; p < 2; ++p) {  // issue next chunk under MFMA
                    int flat = tid + p * 512;
                    int r = flat >> 2, j = flat & 3;
                    wreg[p] = *(const s16x8*)&wfT[(size_t)r * H_F + (kc + 1) * 32 + j * 8];
                }
            }
            int k0 = kc * 32 + ksel;
            s16x8 ah4[4];
            #pragma unroll
            for (int rf = 0; rf < 4; ++rf) {
                int row = rf * 16 + rsel;
                ah4[rf] = *(const s16x8*)&nsH[row * 256 + (k0 ^ ((row & 7) << 3))];
            }
            #pragma unroll
            for (int cf = 0; cf < 2; ++cf) {
                s16x8 bh = *(const s16x8*)&Wcur[(w * 32 + cf * 16 + rsel) * LDW + ksel];
                #pragma unroll
                for (int rf = 0; rf < 4; ++rf)
                    acc[rf][cf] = __builtin_amdgcn_mfma_f32_16x16x32_bf16(ah4[rf], bh, acc[rf][cf], 0, 0, 0);
            }
            cur ^= 1;
        }
        __syncthreads();  // drain Wb1 reads before next hop's A-stage overwrites it
    }
    // ---- final: out = relu(acc + bf), written once ----
    #pragma unroll
    for (int cf = 0; cf < 2; ++cf) {
        int col = w * 32 + cf * 16 + ccol;
        float bb = bf[col];
        #pragma unroll
        for (int rf = 0; rf < 4; ++rf)
            #pragma unroll
            for (int ii = 0; ii < 4; ++ii) {
                int gm = m0 + rf * 16 + crow + ii;
                if (gm < N_NODES)
                    out[(size_t)gm * H_F + col] = fmaxf(acc[rf][cf][ii] + bb, 0.f);
            }
    }
}

extern "C" void kernel_launch(void* const* d_in, const int* in_sizes, int n_in,
                              void* d_out, int out_size, void* d_ws, size_t ws_size,
                              hipStream_t stream) {
    const int* ei = (const int*)d_in[0];
    const int* rows = ei;
    const int* cols = ei + N_EDGES;
    const float* feat = (const float*)d_in[1];
    const float* Ws = (const float*)d_in[2];
    const float* bs = (const float*)d_in[3];
    const float* Wf = (const float*)d_in[4];
    const float* bf = (const float*)d_in[5];
    float* out = (float*)d_out;

    // workspace layout (~84 MB)
    float* h0 = (float*)d_ws;                      // 4 x 4,800,000 f32
    float* h1 = h0 + (size_t)N_NODES * IN_F;
    float* h2 = h1 + (size_t)N_NODES * IN_F;
    float* h3 = h2 + (size_t)N_NODES * IN_F;
    ushort* WsT = (ushort*)(h3 + (size_t)N_NODES * IN_F);  // 98,304 u16
    ushort* WfT = WsT + N_NIE * IN_F * H_F;                // 262,144 u16
    float* dinv = (float*)(WfT + N_NIE * H_F * H_F);       // 50,000 f32
    int* rowptr = (int*)(dinv + N_NODES);                  // 50,004 i32
    int* bsum = rowptr + 50004;                            // 256 i32
    int* boff = bsum + 256;                                // 256 i32
    int2* cw = (int2*)(boff + 256);                        // 800,000 int2
    // CSR-build temporaries aliased into h1 (h1 written only later, by spmm)
    int* cnt = (int*)h1;
    int* cursor = cnt + N_NODES;

    hipMemsetAsync(cnt, 0, N_NODES * sizeof(int), stream);
    k_count<<<(N_EDGES / 2 + 255) / 256, 256, 0, stream>>>(rows, cols, cnt);
    k_scan1<<<SCAN_NB, 256, 0, stream>>>(cnt, rowptr, bsum);
    k_scan2<<<1, 256, 0, stream>>>(bsum, boff, rowptr);
    k_scan3<<<SCAN_NB, 256, 0, stream>>>(boff, cnt, rowptr, cursor, dinv);
    k_scatter<<<(N_EDGES + 255) / 256, 256, 0, stream>>>(rows, cols, dinv, cursor, cw);
    k_wsplit<<<(N_NIE * IN_F * H_F + 255) / 256, 256, 0, stream>>>(Ws, WsT, IN_F, H_F,
                                                                   N_NIE * IN_F * H_F);
    k_wsplit<<<(N_NIE * H_F * H_F + 255) / 256, 256, 0, stream>>>(Wf, WfT, H_F, H_F,
                                                                  N_NIE * H_F * H_F);
    k_norm<<<(N_NODES + 3) / 4, 256, 0, stream>>>(feat, h0);

    // hop chain first (h1..h3), then one fused GEMM pass
    k_spmm_csr<<<(N_NODES * 32 + 255) / 256, 256, 0, stream>>>(rowptr, cw, dinv, h0, h1);
    k_spmm_csr<<<(N_NODES * 32 + 255) / 256, 256, 0, stream>>>(rowptr, cw, dinv, h1, h2);
    k_spmm_csr<<<(N_NODES * 32 + 255) / 256, 256, 0, stream>>>(rowptr, cw, dinv, h2, h3);
    k_mega<<<NBLK, 512, 0, stream>>>(h0, h1, h2, h3, WsT, bs, WfT, bf, out);
}

// Round 14
// 357.432 us; speedup vs baseline: 1.7555x; 1.0089x over previous
//
#include <hip/hip_runtime.h>

#define N_NODES 50000
#define N_EDGES 800000
#define IN_F 96
#define H_F 256
#define N_NIE 4
#define SCAN_NB 196   // ceil(50000/256)
#define BM 64         // mega rows per block
#define NBLK 782      // ceil(50000/64)
#define LDA1 104      // A-lds / Bs stride (shorts): 208B rows
#define LDW 40        // W-stage stride (shorts): 80B rows, 16B-aligned

typedef float f32x4 __attribute__((ext_vector_type(4)));
typedef short s16x8 __attribute__((ext_vector_type(8)));
typedef unsigned short ushort;

__device__ __forceinline__ ushort bf16_rne(float f) {
    unsigned u = __float_as_uint(f);
    u += 0x7fffu + ((u >> 16) & 1u);
    return (ushort)(u >> 16);
}
__device__ __forceinline__ float bf16_f(ushort h) {
    return __uint_as_float(((unsigned)h) << 16);
}

// ---------------- CSR build ----------------
__global__ __launch_bounds__(256) void k_count(const int* __restrict__ rows,
                                               const int* __restrict__ cols,
                                               int* __restrict__ cnt) {
    int i = blockIdx.x * 256 + threadIdx.x;
    if (i >= N_EDGES / 2) return;
    int2 r2 = ((const int2*)rows)[i];
    int2 c2 = ((const int2*)cols)[i];
    if (r2.x != c2.x) atomicAdd(&cnt[r2.x], 1);
    if (r2.y != c2.y) atomicAdd(&cnt[r2.y], 1);
}

__global__ __launch_bounds__(256) void k_scan1(const int* __restrict__ cnt,
                                               int* __restrict__ rowptr,
                                               int* __restrict__ bsum) {
    __shared__ int s[256];
    int t = threadIdx.x, e = blockIdx.x * 256 + t;
    int v = (e < N_NODES) ? cnt[e] : 0;
    s[t] = v;
    __syncthreads();
    #pragma unroll
    for (int off = 1; off < 256; off <<= 1) {
        int nv = (t >= off) ? s[t - off] : 0;
        __syncthreads();
        s[t] += nv;
        __syncthreads();
    }
    if (e < N_NODES) rowptr[e] = s[t] - v;
    if (t == 255) bsum[blockIdx.x] = s[255];
}

__global__ __launch_bounds__(256) void k_scan2(int* __restrict__ bsum,
                                               int* __restrict__ boff,
                                               int* __restrict__ rowptr) {
    __shared__ int s[256];
    int t = threadIdx.x;
    int v = (t < SCAN_NB) ? bsum[t] : 0;
    s[t] = v;
    __syncthreads();
    #pragma unroll
    for (int off = 1; off < 256; off <<= 1) {
        int nv = (t >= off) ? s[t - off] : 0;
        __syncthreads();
        s[t] += nv;
        __syncthreads();
    }
    if (t < SCAN_NB) boff[t] = s[t] - v;
    if (t == 255) rowptr[N_NODES] = s[255];
}

__global__ __launch_bounds__(256) void k_scan3(const int* __restrict__ boff,
                                               const int* __restrict__ cnt,
                                               int* __restrict__ rowptr,
                                               int* __restrict__ cursor,
                                               float* __restrict__ dinv) {
    int e = blockIdx.x * 256 + threadIdx.x;
    if (e >= N_NODES) return;
    int r = rowptr[e] + boff[blockIdx.x];
    rowptr[e] = r;
    cursor[e] = r;
    dinv[e] = rsqrtf((float)cnt[e] + 1.0f);
}

// single-pass scatter; packs (col, dinv[col]); non-temporal store to avoid
// multi-XCD dirty-line writeback amplification (cw is stream-read later)
__global__ __launch_bounds__(256) void k_scatter(const int* __restrict__ rows,
                                                 const int* __restrict__ cols,
                                                 const float* __restrict__ dinv,
                                                 int* __restrict__ cursor,
                                                 int2* __restrict__ cw) {
    int e = blockIdx.x * 256 + threadIdx.x;
    if (e >= N_EDGES) return;
    int r = rows[e], c = cols[e];
    if (r == c) return;  // set_diag zeroes pre-existing diagonal entries
    int p = atomicAdd(&cursor[r], 1);
    long long v = ((long long)(unsigned)__float_as_int(dinv[c]) << 32) | (unsigned)c;
    __builtin_nontemporal_store(v, (long long*)&cw[p]);
}

// ---------------- weight transpose + bf16 round (hi only) ----------------
__global__ __launch_bounds__(256) void k_wsplit(const float* __restrict__ src,
                                                ushort* __restrict__ dh,
                                                int K, int N, int total) {
    int idx = blockIdx.x * 256 + threadIdx.x;
    if (idx >= total) return;
    int kn = K * N;
    int g = idx / kn, rem = idx - g * kn;
    int k = rem / N, n = rem - k * N;
    dh[g * kn + n * K + k] = bf16_rne(src[idx]);
}

// ---------------- row-normalize features ----------------
__global__ __launch_bounds__(256) void k_norm(const float* __restrict__ feat,
                                              float* __restrict__ x) {
    int wid = (blockIdx.x * 256 + threadIdx.x) >> 6;
    int lane = threadIdx.x & 63;
    if (wid >= N_NODES) return;
    const float* fr = feat + (size_t)wid * IN_F;
    float v0 = (lane < IN_F) ? fr[lane] : 0.0f;
    float v1 = (lane < IN_F - 64) ? fr[64 + lane] : 0.0f;
    float ss = v0 * v0 + v1 * v1;
    #pragma unroll
    for (int o = 32; o; o >>= 1) ss += __shfl_xor(ss, o, 64);
    float inv = 1.0f / fmaxf(sqrtf(ss), 1e-12f);
    float* xr = x + (size_t)wid * IN_F;
    if (lane < IN_F) xr[lane] = v0 * inv;
    if (lane < IN_F - 64) xr[64 + lane] = v1 * inv;
}

// ---------------- CSR SpMM: 32-lane group/row, packed (c,w), unroll 4 ----------------
__global__ __launch_bounds__(256) void k_spmm_csr(const int* __restrict__ rowptr,
                                                  const int2* __restrict__ cw,
                                                  const float* __restrict__ dinv,
                                                  const float* __restrict__ x,
                                                  float* __restrict__ y) {
    int g = (blockIdx.x * 256 + threadIdx.x) >> 5;
    if (g >= N_NODES) return;
    int l = threadIdx.x & 31;  // lane handles feats l, l+32, l+64
    float dr = dinv[g];
    const float* xg = x + (size_t)g * IN_F;
    float s0 = xg[l], s1 = xg[l + 32], s2 = xg[l + 64];
    float a0 = 0.f, a1 = 0.f, a2 = 0.f;
    float b0 = 0.f, b1 = 0.f, b2 = 0.f;
    float c0 = 0.f, c1 = 0.f, c2 = 0.f;
    float d0 = 0.f, d1 = 0.f, d2 = 0.f;
    int k = rowptr[g], e = rowptr[g + 1];
    for (; k + 3 < e; k += 4) {  // 4 independent gather chains in flight
        int2 p0 = cw[k], p1 = cw[k + 1], p2 = cw[k + 2], p3 = cw[k + 3];
        const float* x0 = x + (size_t)p0.x * IN_F;
        const float* x1 = x + (size_t)p1.x * IN_F;
        const float* x2 = x + (size_t)p2.x * IN_F;
        const float* x3 = x + (size_t)p3.x * IN_F;
        float w0 = __int_as_float(p0.y), w1 = __int_as_float(p1.y);
        float w2 = __int_as_float(p2.y), w3 = __int_as_float(p3.y);
        a0 += x0[l] * w0; a1 += x0[l + 32] * w0; a2 += x0[l + 64] * w0;
        b0 += x1[l] * w1; b1 += x1[l + 32] * w1; b2 += x1[l + 64] * w1;
        c0 += x2[l] * w2; c1 += x2[l + 32] * w2; c2 += x2[l + 64] * w2;
        d0 += x3[l] * w3; d1 += x3[l + 32] * w3; d2 += x3[l + 64] * w3;
    }
    for (; k < e; ++k) {
        int2 p0 = cw[k];
        float w0 = __int_as_float(p0.y);
        const float* x0 = x + (size_t)p0.x * IN_F;
        a0 += x0[l] * w0; a1 += x0[l + 32] * w0; a2 += x0[l + 64] * w0;
    }
    float* yr = y + (size_t)g * IN_F;
    yr[l]      = dr * ((a0 + b0) + (c0 + d0) + dr * s0);
    yr[l + 32] = dr * ((a1 + b1) + (c1 + d1) + dr * s1);
    yr[l + 64] = dr * ((a2 + b2) + (c2 + d2) + dr * s2);
}

// ---------------- MEGA v6: BM=64, swizzled nsH, W-dbuf aliased onto dead A region ----------------
// out = relu( sum_i relu(h_i @ WsT_i + bs_i) @ WfT_i + bf ), written once.
// LDS 79.9 KB -> 2 blocks/CU; 1 barrier/kc (dbuf); weight re-reads halved vs BM=32.
__global__ __launch_bounds__(512, 4) void k_mega(const float* __restrict__ h0,
                                                 const float* __restrict__ h1,
                                                 const float* __restrict__ h2,
                                                 const float* __restrict__ h3,
                                                 const ushort* __restrict__ WsT,
                                                 const float* __restrict__ bs,
                                                 const ushort* __restrict__ WfT,
                                                 const float* __restrict__ bf,
                                                 float* __restrict__ out) {
    __shared__ ushort SM[39936];        // 79.87 KB total
    ushort* nsH = SM;                   // [64][256] swizzled (16384 shorts)
    ushort* Ah  = SM + 16384;           // [64][LDA1] (6656)
    ushort* Al  = SM + 23040;           // [64][LDA1] (6656)
    ushort* U   = SM + 29696;           // 10240: Wbuf0 [256][LDW] / Bs [64][LDA1] overlay
    ushort* Wb0 = U;
    ushort* Wb1 = Ah;                   // aliases A region (dead during phase 2)

    int m0 = blockIdx.x * BM;
    int tid = threadIdx.x;
    int lane = tid & 63, w = tid >> 6;
    int rsel = lane & 15, g = lane >> 4, ksel = g * 8;
    int crow = g * 4, ccol = rsel;
    int rw0 = (w & 3) * 16;   // phase-1 row-fragment base
    int cwb = (w >> 2) * 32;  // phase-1 col base within each 64-col chunk

    f32x4 acc[4][2] = {};  // persistent: rows rf*16.., cols w*32+cf*16..

    for (int hop = 0; hop < N_NIE; ++hop) {
        const float* A = (hop == 0) ? h0 : (hop == 1) ? h1 : (hop == 2) ? h2 : h3;
        const ushort* wsT = WsT + hop * IN_F * H_F;  // [n=256][k=96] bf16
        const ushort* wfT = WfT + hop * H_F * H_F;   // [n=256][k=256] bf16
        const float* bsi = bs + hop * H_F;

        // ---- stage A (fp32 -> split bf16) to LDS, once per block (768 items) ----
        #pragma unroll
        for (int p = 0; p < 2; ++p) {
            int flat = tid + p * 512;
            if (flat < 768) {
                int r = flat / 12, j = flat - r * 12;
                int gm = m0 + r;
                float4 v0 = make_float4(0.f, 0.f, 0.f, 0.f), v1 = v0;
                if (gm < N_NODES) {
                    v0 = *(const float4*)&A[(size_t)gm * IN_F + j * 8];
                    v1 = *(const float4*)&A[(size_t)gm * IN_F + j * 8 + 4];
                }
                float vv[8] = {v0.x, v0.y, v0.z, v0.w, v1.x, v1.y, v1.z, v1.w};
                s16x8 ah, al;
                #pragma unroll
                for (int q = 0; q < 8; ++q) {
                    ushort hq = bf16_rne(vv[q]);
                    ah[q] = (short)hq;
                    al[q] = (short)bf16_rne(vv[q] - bf16_f(hq));
                }
                *(s16x8*)&Ah[r * LDA1 + j * 8] = ah;
                *(s16x8*)&Al[r * LDA1 + j * 8] = al;
            }
        }
        // ---- phase 1: nsH[64][256] = relu(A @ WsT + bs), 4 chunks of 64 cols ----
        #pragma unroll
        for (int c = 0; c < 4; ++c) {
            __syncthreads();  // U free (prev reads done); orders A-stage (c=0)
            #pragma unroll
            for (int p = 0; p < 2; ++p) {
                int flat = tid + p * 512;  // 768 items: [64][12]
                if (flat < 768) {
                    int r = flat / 12, j = flat - r * 12;
                    *(s16x8*)&U[r * LDA1 + j * 8] =
                        *(const s16x8*)&wsT[(size_t)(c * 64 + r) * IN_F + j * 8];
                }
            }
            __syncthreads();  // Bs + A-lds visible
            f32x4 ac[2] = {};
            #pragma unroll
            for (int ks = 0; ks < 3; ++ks) {
                int k0 = ks * 32 + ksel;
                s16x8 ah = *(const s16x8*)&Ah[(rw0 + rsel) * LDA1 + k0];
                s16x8 al = *(const s16x8*)&Al[(rw0 + rsel) * LDA1 + k0];
                s16x8 b0 = *(const s16x8*)&U[(cwb + rsel) * LDA1 + k0];
                s16x8 b1 = *(const s16x8*)&U[(cwb + 16 + rsel) * LDA1 + k0];
                ac[0] = __builtin_amdgcn_mfma_f32_16x16x32_bf16(ah, b0, ac[0], 0, 0, 0);
                ac[0] = __builtin_amdgcn_mfma_f32_16x16x32_bf16(al, b0, ac[0], 0, 0, 0);
                ac[1] = __builtin_amdgcn_mfma_f32_16x16x32_bf16(ah, b1, ac[1], 0, 0, 0);
                ac[1] = __builtin_amdgcn_mfma_f32_16x16x32_bf16(al, b1, ac[1], 0, 0, 0);
            }
            #pragma unroll
            for (int cf = 0; cf < 2; ++cf) {
                int col = c * 64 + cwb + cf * 16 + ccol;
                float bb = bsi[col];
                #pragma unroll
                for (int ii = 0; ii < 4; ++ii) {
                    int row = rw0 + crow + ii;
                    nsH[row * 256 + (col ^ ((row & 7) << 3))] =
                        bf16_rne(fmaxf(ac[cf][ii] + bb, 0.f));
                }
            }
        }
        // ---- phase 2: acc += ns @ WfT, dbuf W (buf1 aliases A region), 1 bar/kc ----
        s16x8 wreg[2];
        #pragma unroll
        for (int p = 0; p < 2; ++p) {  // preload kc=0
            int flat = tid + p * 512;
            int r = flat >> 2, j = flat & 3;
            wreg[p] = *(const s16x8*)&wfT[(size_t)r * H_F + j * 8];
        }
        __syncthreads();  // nsH complete; Bs/A reads drained -> U & A regions writable
        int cur = 0;
        #pragma unroll
        for (int kc = 0; kc < 8; ++kc) {
            ushort* Wcur = cur ? Wb1 : Wb0;
            #pragma unroll
            for (int p = 0; p < 2; ++p) {
                int flat = tid + p * 512;
                int r = flat >> 2, j = flat & 3;
                *(s16x8*)&Wcur[r * LDW + j * 8] = wreg[p];
            }
            __syncthreads();  // Wcur visible; other-buf reads already drained
            if (kc < 7) {
                #pragma unroll
                for (int p = 0; p < 2; ++p) {  // issue next chunk under MFMA
                    int flat = tid + p * 512;
                    int r = flat >> 2, j = flat & 3;
                    wreg[p] = *(const s16x8*)&wfT[(size_t)r * H_F + (kc + 1) * 32 + j * 8];
                }
            }
            int k0 = kc * 32 + ksel;
            s16x8 ah4[4];
            #pragma unroll
            for (int rf = 0; rf < 4; ++rf) {
                int row = rf * 16 + rsel;
                ah4[rf] = *(const s16x8*)&nsH[row * 256 + (k0 ^ ((row & 7) << 3))];
            }
            #pragma unroll
            for (int cf = 0; cf < 2; ++cf) {
                s16x8 bh = *(const s16x8*)&Wcur[(w * 32 + cf * 16 + rsel) * LDW + ksel];
                #pragma unroll
                for (int rf = 0; rf < 4; ++rf)
                    acc[rf][cf] = __builtin_amdgcn_mfma_f32_16x16x32_bf16(ah4[rf], bh, acc[rf][cf], 0, 0, 0);
            }
            cur ^= 1;
        }
        __syncthreads();  // drain Wb1 reads before next hop's A-stage overwrites it
    }
    // ---- final: out = relu(acc + bf), written once ----
    #pragma unroll
    for (int cf = 0; cf < 2; ++cf) {
        int col = w * 32 + cf * 16 + ccol;
        float bb = bf[col];
        #pragma unroll
        for (int rf = 0; rf < 4; ++rf)
            #pragma unroll
            for (int ii = 0; ii < 4; ++ii) {
                int gm = m0 + rf * 16 + crow + ii;
                if (gm < N_NODES)
                    out[(size_t)gm * H_F + col] = fmaxf(acc[rf][cf][ii] + bb, 0.f);
            }
    }
}

extern "C" void kernel_launch(void* const* d_in, const int* in_sizes, int n_in,
                              void* d_out, int out_size, void* d_ws, size_t ws_size,
                              hipStream_t stream) {
    const int* ei = (const int*)d_in[0];
    const int* rows = ei;
    const int* cols = ei + N_EDGES;
    const float* feat = (const float*)d_in[1];
    const float* Ws = (const float*)d_in[2];
    const float* bs = (const float*)d_in[3];
    const float* Wf = (const float*)d_in[4];
    const float* bf = (const float*)d_in[5];
    float* out = (float*)d_out;

    // workspace layout (~84 MB)
    float* h0 = (float*)d_ws;                      // 4 x 4,800,000 f32
    float* h1 = h0 + (size_t)N_NODES * IN_F;
    float* h2 = h1 + (size_t)N_NODES * IN_F;
    float* h3 = h2 + (size_t)N_NODES * IN_F;
    ushort* WsT = (ushort*)(h3 + (size_t)N_NODES * IN_F);  // 98,304 u16
    ushort* WfT = WsT + N_NIE * IN_F * H_F;                // 262,144 u16
    float* dinv = (float*)(WfT + N_NIE * H_F * H_F);       // 50,000 f32
    int* rowptr = (int*)(dinv + N_NODES);                  // 50,004 i32
    int* bsum = rowptr + 50004;                            // 256 i32
    int* boff = bsum + 256;                                // 256 i32
    int2* cw = (int2*)(boff + 256);                        // 800,000 int2
    // CSR-build temporaries aliased into h1 (h1 written only later, by spmm)
    int* cnt = (int*)h1;
    int* cursor = cnt + N_NODES;

    hipMemsetAsync(cnt, 0, N_NODES * sizeof(int), stream);
    k_count<<<(N_EDGES / 2 + 255) / 256, 256, 0, stream>>>(rows, cols, cnt);
    k_scan1<<<SCAN_NB, 256, 0, stream>>>(cnt, rowptr, bsum);
    k_scan2<<<1, 256, 0, stream>>>(bsum, boff, rowptr);
    k_scan3<<<SCAN_NB, 256, 0, stream>>>(boff, cnt, rowptr, cursor, dinv);
    k_scatter<<<(N_EDGES + 255) / 256, 256, 0, stream>>>(rows, cols, dinv, cursor, cw);
    k_wsplit<<<(N_NIE * IN_F * H_F + 255) / 256, 256, 0, stream>>>(Ws, WsT, IN_F, H_F,
                                                                   N_NIE * IN_F * H_F);
    k_wsplit<<<(N_NIE * H_F * H_F + 255) / 256, 256, 0, stream>>>(Wf, WfT, H_F, H_F,
                                                                  N_NIE * H_F * H_F);
    k_norm<<<(N_NODES + 3) / 4, 256, 0, stream>>>(feat, h0);

    // hop chain first (h1..h3), then one fused GEMM pass
    k_spmm_csr<<<(N_NODES * 32 + 255) / 256, 256, 0, stream>>>(rowptr, cw, dinv, h0, h1);
    k_spmm_csr<<<(N_NODES * 32 + 255) / 256, 256, 0, stream>>>(rowptr, cw, dinv, h1, h2);
    k_spmm_csr<<<(N_NODES * 32 + 255) / 256, 256, 0, stream>>>(rowptr, cw, dinv, h2, h3);
    k_mega<<<NBLK, 512, 0, stream>>>(h0, h1, h2, h3, WsT, bs, WfT, bf, out);
}

// Round 15
// 320.009 us; speedup vs baseline: 1.9608x; 1.1169x over previous
//
#include <hip/hip_runtime.h>

#define N_NODES 50000
#define N_EDGES 800000
#define IN_F 96
#define H_F 256
#define N_NIE 4
#define SCAN_NB 196   // ceil(50000/256)
#define BM 64         // mega rows per block
#define NBLK 782      // ceil(50000/64)
#define LDA1 104      // A-lds / Bs stride (shorts): 208B rows
#define LDW 40        // W-stage stride (shorts): 80B rows, 16B-aligned

typedef float f32x4 __attribute__((ext_vector_type(4)));
typedef short s16x8 __attribute__((ext_vector_type(8)));
typedef unsigned short ushort;

__device__ __forceinline__ ushort bf16_rne(float f) {
    unsigned u = __float_as_uint(f);
    u += 0x7fffu + ((u >> 16) & 1u);
    return (ushort)(u >> 16);
}
__device__ __forceinline__ float bf16_f(ushort h) {
    return __uint_as_float(((unsigned)h) << 16);
}

// ---------------- CSR build ----------------
__global__ __launch_bounds__(256) void k_count(const int* __restrict__ rows,
                                               const int* __restrict__ cols,
                                               int* __restrict__ cnt) {
    int i = blockIdx.x * 256 + threadIdx.x;
    if (i >= N_EDGES / 2) return;
    int2 r2 = ((const int2*)rows)[i];
    int2 c2 = ((const int2*)cols)[i];
    if (r2.x != c2.x) atomicAdd(&cnt[r2.x], 1);
    if (r2.y != c2.y) atomicAdd(&cnt[r2.y], 1);
}

__global__ __launch_bounds__(256) void k_scan1(const int* __restrict__ cnt,
                                               int* __restrict__ rowptr,
                                               int* __restrict__ bsum) {
    __shared__ int s[256];
    int t = threadIdx.x, e = blockIdx.x * 256 + t;
    int v = (e < N_NODES) ? cnt[e] : 0;
    s[t] = v;
    __syncthreads();
    #pragma unroll
    for (int off = 1; off < 256; off <<= 1) {
        int nv = (t >= off) ? s[t - off] : 0;
        __syncthreads();
        s[t] += nv;
        __syncthreads();
    }
    if (e < N_NODES) rowptr[e] = s[t] - v;
    if (t == 255) bsum[blockIdx.x] = s[255];
}

__global__ __launch_bounds__(256) void k_scan2(int* __restrict__ bsum,
                                               int* __restrict__ boff,
                                               int* __restrict__ rowptr) {
    __shared__ int s[256];
    int t = threadIdx.x;
    int v = (t < SCAN_NB) ? bsum[t] : 0;
    s[t] = v;
    __syncthreads();
    #pragma unroll
    for (int off = 1; off < 256; off <<= 1) {
        int nv = (t >= off) ? s[t - off] : 0;
        __syncthreads();
        s[t] += nv;
        __syncthreads();
    }
    if (t < SCAN_NB) boff[t] = s[t] - v;
    if (t == 255) rowptr[N_NODES] = s[255];
}

__global__ __launch_bounds__(256) void k_scan3(const int* __restrict__ boff,
                                               const int* __restrict__ cnt,
                                               int* __restrict__ rowptr,
                                               int* __restrict__ cursor,
                                               float* __restrict__ dinv) {
    int e = blockIdx.x * 256 + threadIdx.x;
    if (e >= N_NODES) return;
    int r = rowptr[e] + boff[blockIdx.x];
    rowptr[e] = r;
    cursor[e] = r;
    dinv[e] = rsqrtf((float)cnt[e] + 1.0f);
}

// single-pass scatter; packs (col, dinv[col])
__global__ __launch_bounds__(256) void k_scatter(const int* __restrict__ rows,
                                                 const int* __restrict__ cols,
                                                 const float* __restrict__ dinv,
                                                 int* __restrict__ cursor,
                                                 int2* __restrict__ cw) {
    int e = blockIdx.x * 256 + threadIdx.x;
    if (e >= N_EDGES) return;
    int r = rows[e], c = cols[e];
    if (r == c) return;  // set_diag zeroes pre-existing diagonal entries
    int p = atomicAdd(&cursor[r], 1);
    long long v = ((long long)(unsigned)__float_as_int(dinv[c]) << 32) | (unsigned)c;
    __builtin_nontemporal_store(v, (long long*)&cw[p]);
}

// ---------------- weight transpose + bf16 round (hi only) ----------------
__global__ __launch_bounds__(256) void k_wsplit(const float* __restrict__ src,
                                                ushort* __restrict__ dh,
                                                int K, int N, int total) {
    int idx = blockIdx.x * 256 + threadIdx.x;
    if (idx >= total) return;
    int kn = K * N;
    int g = idx / kn, rem = idx - g * kn;
    int k = rem / N, n = rem - k * N;
    dh[g * kn + n * K + k] = bf16_rne(src[idx]);
}

// ---------------- row-normalize features -> bf16 ----------------
__global__ __launch_bounds__(256) void k_norm(const float* __restrict__ feat,
                                              ushort* __restrict__ x) {
    int wid = (blockIdx.x * 256 + threadIdx.x) >> 6;
    int lane = threadIdx.x & 63;
    if (wid >= N_NODES) return;
    const float* fr = feat + (size_t)wid * IN_F;
    float v0 = (lane < IN_F) ? fr[lane] : 0.0f;
    float v1 = (lane < IN_F - 64) ? fr[64 + lane] : 0.0f;
    float ss = v0 * v0 + v1 * v1;
    #pragma unroll
    for (int o = 32; o; o >>= 1) ss += __shfl_xor(ss, o, 64);
    float inv = 1.0f / fmaxf(sqrtf(ss), 1e-12f);
    ushort* xr = x + (size_t)wid * IN_F;
    if (lane < IN_F) xr[lane] = bf16_rne(v0 * inv);
    if (lane < IN_F - 64) xr[64 + lane] = bf16_rne(v1 * inv);
}

// ---------------- CSR SpMM: bf16 gather, fp32 accum, bf16 store; unroll 4 ----------------
__global__ __launch_bounds__(256) void k_spmm_csr(const int* __restrict__ rowptr,
                                                  const int2* __restrict__ cw,
                                                  const float* __restrict__ dinv,
                                                  const ushort* __restrict__ x,
                                                  ushort* __restrict__ y) {
    int g = (blockIdx.x * 256 + threadIdx.x) >> 5;
    if (g >= N_NODES) return;
    int l = threadIdx.x & 31;  // lane handles feats l, l+32, l+64
    float dr = dinv[g];
    const ushort* xg = x + (size_t)g * IN_F;
    float s0 = bf16_f(xg[l]), s1 = bf16_f(xg[l + 32]), s2 = bf16_f(xg[l + 64]);
    float a0 = 0.f, a1 = 0.f, a2 = 0.f;
    float b0 = 0.f, b1 = 0.f, b2 = 0.f;
    float c0 = 0.f, c1 = 0.f, c2 = 0.f;
    float d0 = 0.f, d1 = 0.f, d2 = 0.f;
    int k = rowptr[g], e = rowptr[g + 1];
    for (; k + 3 < e; k += 4) {  // 4 independent gather chains in flight
        int2 p0 = cw[k], p1 = cw[k + 1], p2 = cw[k + 2], p3 = cw[k + 3];
        const ushort* x0 = x + (size_t)p0.x * IN_F;
        const ushort* x1 = x + (size_t)p1.x * IN_F;
        const ushort* x2 = x + (size_t)p2.x * IN_F;
        const ushort* x3 = x + (size_t)p3.x * IN_F;
        float w0 = __int_as_float(p0.y), w1 = __int_as_float(p1.y);
        float w2 = __int_as_float(p2.y), w3 = __int_as_float(p3.y);
        a0 += bf16_f(x0[l]) * w0; a1 += bf16_f(x0[l + 32]) * w0; a2 += bf16_f(x0[l + 64]) * w0;
        b0 += bf16_f(x1[l]) * w1; b1 += bf16_f(x1[l + 32]) * w1; b2 += bf16_f(x1[l + 64]) * w1;
        c0 += bf16_f(x2[l]) * w2; c1 += bf16_f(x2[l + 32]) * w2; c2 += bf16_f(x2[l + 64]) * w2;
        d0 += bf16_f(x3[l]) * w3; d1 += bf16_f(x3[l + 32]) * w3; d2 += bf16_f(x3[l + 64]) * w3;
    }
    for (; k < e; ++k) {
        int2 p0 = cw[k];
        float w0 = __int_as_float(p0.y);
        const ushort* x0 = x + (size_t)p0.x * IN_F;
        a0 += bf16_f(x0[l]) * w0; a1 += bf16_f(x0[l + 32]) * w0; a2 += bf16_f(x0[l + 64]) * w0;
    }
    ushort* yr = y + (size_t)g * IN_F;
    yr[l]      = bf16_rne(dr * ((a0 + b0) + (c0 + d0) + dr * s0));
    yr[l + 32] = bf16_rne(dr * ((a1 + b1) + (c1 + d1) + dr * s1));
    yr[l + 64] = bf16_rne(dr * ((a2 + b2) + (c2 + d2) + dr * s2));
}

// ---------------- MEGA v7: bf16 A (no split), swizzled nsH, W-dbuf, 73.7 KB LDS ----------------
// out = relu( sum_i relu(h_i @ WsT_i + bs_i) @ WfT_i + bf ), written once.
__global__ __launch_bounds__(512, 4) void k_mega(const ushort* __restrict__ h0,
                                                 const ushort* __restrict__ h1,
                                                 const ushort* __restrict__ h2,
                                                 const ushort* __restrict__ h3,
                                                 const ushort* __restrict__ WsT,
                                                 const float* __restrict__ bs,
                                                 const ushort* __restrict__ WfT,
                                                 const float* __restrict__ bf,
                                                 float* __restrict__ out) {
    __shared__ ushort SM[36864];        // 73.7 KB total
    ushort* nsH = SM;                   // [64][256] swizzled (16384)
    ushort* Wb0 = SM + 16384;           // 10240 (phase-1 Bs overlay)
    ushort* Wb1 = SM + 26624;           // 10240 (phase-1 Ah overlay)
    ushort* Bs = Wb0;                   // [64][LDA1] = 6656 <= 10240
    ushort* Ah = Wb1;                   // [64][LDA1] = 6656 <= 10240

    int m0 = blockIdx.x * BM;
    int tid = threadIdx.x;
    int lane = tid & 63, w = tid >> 6;
    int rsel = lane & 15, g = lane >> 4, ksel = g * 8;
    int crow = g * 4, ccol = rsel;
    int rw0 = (w & 3) * 16;   // phase-1 row-fragment base
    int cwb = (w >> 2) * 32;  // phase-1 col base within each 64-col chunk

    f32x4 acc[4][2] = {};  // persistent: rows rf*16.., cols w*32+cf*16..

    for (int hop = 0; hop < N_NIE; ++hop) {
        const ushort* A = (hop == 0) ? h0 : (hop == 1) ? h1 : (hop == 2) ? h2 : h3;
        const ushort* wsT = WsT + hop * IN_F * H_F;  // [n=256][k=96] bf16
        const ushort* wfT = WfT + hop * H_F * H_F;   // [n=256][k=256] bf16
        const float* bsi = bs + hop * H_F;

        // ---- stage A (bf16, plain copy) to LDS: 768 s16x8 items [64][12] ----
        #pragma unroll
        for (int p = 0; p < 2; ++p) {
            int flat = tid + p * 512;
            if (flat < 768) {
                int r = flat / 12, j = flat - r * 12;
                int gm = m0 + r;
                s16x8 v = {0, 0, 0, 0, 0, 0, 0, 0};
                if (gm < N_NODES) v = *(const s16x8*)&A[(size_t)gm * IN_F + j * 8];
                *(s16x8*)&Ah[r * LDA1 + j * 8] = v;
            }
        }
        // ---- phase 1: nsH[64][256] = relu(A @ WsT + bs), 4 chunks of 64 cols ----
        #pragma unroll
        for (int c = 0; c < 4; ++c) {
            __syncthreads();  // Bs region free (prev reads done); orders A-stage (c=0)
            #pragma unroll
            for (int p = 0; p < 2; ++p) {
                int flat = tid + p * 512;  // 768 items: [64][12]
                if (flat < 768) {
                    int r = flat / 12, j = flat - r * 12;
                    *(s16x8*)&Bs[r * LDA1 + j * 8] =
                        *(const s16x8*)&wsT[(size_t)(c * 64 + r) * IN_F + j * 8];
                }
            }
            __syncthreads();  // Bs + A-lds visible
            f32x4 ac[2] = {};
            #pragma unroll
            for (int ks = 0; ks < 3; ++ks) {
                int k0 = ks * 32 + ksel;
                s16x8 ah = *(const s16x8*)&Ah[(rw0 + rsel) * LDA1 + k0];
                s16x8 b0 = *(const s16x8*)&Bs[(cwb + rsel) * LDA1 + k0];
                s16x8 b1 = *(const s16x8*)&Bs[(cwb + 16 + rsel) * LDA1 + k0];
                ac[0] = __builtin_amdgcn_mfma_f32_16x16x32_bf16(ah, b0, ac[0], 0, 0, 0);
                ac[1] = __builtin_amdgcn_mfma_f32_16x16x32_bf16(ah, b1, ac[1], 0, 0, 0);
            }
            #pragma unroll
            for (int cf = 0; cf < 2; ++cf) {
                int col = c * 64 + cwb + cf * 16 + ccol;
                float bb = bsi[col];
                #pragma unroll
                for (int ii = 0; ii < 4; ++ii) {
                    int row = rw0 + crow + ii;
                    nsH[row * 256 + (col ^ ((row & 7) << 3))] =
                        bf16_rne(fmaxf(ac[cf][ii] + bb, 0.f));
                }
            }
        }
        // ---- phase 2: acc += ns @ WfT, dbuf W (Wb1 aliases A region), 1 bar/kc ----
        s16x8 wreg[2];
        #pragma unroll
        for (int p = 0; p < 2; ++p) {  // preload kc=0
            int flat = tid + p * 512;
            int r = flat >> 2, j = flat & 3;
            wreg[p] = *(const s16x8*)&wfT[(size_t)r * H_F + j * 8];
        }
        __syncthreads();  // nsH complete; Bs/A reads drained -> W regions writable
        int cur = 0;
        #pragma unroll
        for (int kc = 0; kc < 8; ++kc) {
            ushort* Wcur = cur ? Wb1 : Wb0;
            #pragma unroll
            for (int p = 0; p < 2; ++p) {
                int flat = tid + p * 512;
                int r = flat >> 2, j = flat & 3;
                *(s16x8*)&Wcur[r * LDW + j * 8] = wreg[p];
            }
            __syncthreads();  // Wcur visible; other-buf reads already drained
            if (kc < 7) {
                #pragma unroll
                for (int p = 0; p < 2; ++p) {  // issue next chunk under MFMA
                    int flat = tid + p * 512;
                    int r = flat >> 2, j = flat & 3;
                    wreg[p] = *(const s16x8*)&wfT[(size_t)r * H_F + (kc + 1) * 32 + j * 8];
                }
            }
            int k0 = kc * 32 + ksel;
            s16x8 ah4[4];
            #pragma unroll
            for (int rf = 0; rf < 4; ++rf) {
                int row = rf * 16 + rsel;
                ah4[rf] = *(const s16x8*)&nsH[row * 256 + (k0 ^ ((row & 7) << 3))];
            }
            #pragma unroll
            for (int cf = 0; cf < 2; ++cf) {
                s16x8 bh = *(const s16x8*)&Wcur[(w * 32 + cf * 16 + rsel) * LDW + ksel];
                #pragma unroll
                for (int rf = 0; rf < 4; ++rf)
                    acc[rf][cf] = __builtin_amdgcn_mfma_f32_16x16x32_bf16(ah4[rf], bh, acc[rf][cf], 0, 0, 0);
            }
            cur ^= 1;
        }
        __syncthreads();  // drain Wb1 reads before next hop's A-stage overwrites it
    }
    // ---- final: out = relu(acc + bf), written once ----
    #pragma unroll
    for (int cf = 0; cf < 2; ++cf) {
        int col = w * 32 + cf * 16 + ccol;
        float bb = bf[col];
        #pragma unroll
        for (int rf = 0; rf < 4; ++rf)
            #pragma unroll
            for (int ii = 0; ii < 4; ++ii) {
                int gm = m0 + rf * 16 + crow + ii;
                if (gm < N_NODES)
                    out[(size_t)gm * H_F + col] = fmaxf(acc[rf][cf][ii] + bb, 0.f);
            }
    }
}

extern "C" void kernel_launch(void* const* d_in, const int* in_sizes, int n_in,
                              void* d_out, int out_size, void* d_ws, size_t ws_size,
                              hipStream_t stream) {
    const int* ei = (const int*)d_in[0];
    const int* rows = ei;
    const int* cols = ei + N_EDGES;
    const float* feat = (const float*)d_in[1];
    const float* Ws = (const float*)d_in[2];
    const float* bs = (const float*)d_in[3];
    const float* Wf = (const float*)d_in[4];
    const float* bf = (const float*)d_in[5];
    float* out = (float*)d_out;

    // workspace layout (~52 MB)
    ushort* h0 = (ushort*)d_ws;                    // 4 x 4,800,000 u16 (bf16 h chain)
    ushort* h1 = h0 + (size_t)N_NODES * IN_F;
    ushort* h2 = h1 + (size_t)N_NODES * IN_F;
    ushort* h3 = h2 + (size_t)N_NODES * IN_F;
    ushort* WsT = h3 + (size_t)N_NODES * IN_F;     // 98,304 u16
    ushort* WfT = WsT + N_NIE * IN_F * H_F;        // 262,144 u16
    float* dinv = (float*)(WfT + N_NIE * H_F * H_F);  // 50,000 f32
    int* rowptr = (int*)(dinv + N_NODES);          // 50,004 i32
    int* bsum = rowptr + 50004;                    // 256 i32
    int* boff = bsum + 256;                        // 256 i32
    int2* cw = (int2*)(boff + 256);                // 800,000 int2
    // CSR-build temporaries aliased into h1 (h1 written only later, by spmm)
    int* cnt = (int*)h1;
    int* cursor = cnt + N_NODES;

    hipMemsetAsync(cnt, 0, N_NODES * sizeof(int), stream);
    k_count<<<(N_EDGES / 2 + 255) / 256, 256, 0, stream>>>(rows, cols, cnt);
    k_scan1<<<SCAN_NB, 256, 0, stream>>>(cnt, rowptr, bsum);
    k_scan2<<<1, 256, 0, stream>>>(bsum, boff, rowptr);
    k_scan3<<<SCAN_NB, 256, 0, stream>>>(boff, cnt, rowptr, cursor, dinv);
    k_scatter<<<(N_EDGES + 255) / 256, 256, 0, stream>>>(rows, cols, dinv, cursor, cw);
    k_wsplit<<<(N_NIE * IN_F * H_F + 255) / 256, 256, 0, stream>>>(Ws, WsT, IN_F, H_F,
                                                                   N_NIE * IN_F * H_F);
    k_wsplit<<<(N_NIE * H_F * H_F + 255) / 256, 256, 0, stream>>>(Wf, WfT, H_F, H_F,
                                                                  N_NIE * H_F * H_F);
    k_norm<<<(N_NODES + 3) / 4, 256, 0, stream>>>(feat, h0);

    // hop chain first (h1..h3), then one fused GEMM pass
    k_spmm_csr<<<(N_NODES * 32 + 255) / 256, 256, 0, stream>>>(rowptr, cw, dinv, h0, h1);
    k_spmm_csr<<<(N_NODES * 32 + 255) / 256, 256, 0, stream>>>(rowptr, cw, dinv, h1, h2);
    k_spmm_csr<<<(N_NODES * 32 + 255) / 256, 256, 0, stream>>>(rowptr, cw, dinv, h2, h3);
    k_mega<<<NBLK, 512, 0, stream>>>(h0, h1, h2, h3, WsT, bs, WfT, bf, out);
}

// Round 16
// 300.916 us; speedup vs baseline: 2.0852x; 1.0635x over previous
//
#include <hip/hip_runtime.h>

#define N_NODES 50000
#define N_EDGES 800000
#define IN_F 96
#define H_F 256
#define N_NIE 4
#define SCAN_NB 196   // ceil(50000/256)
#define BM 64         // mega rows per block
#define NBLK 782      // ceil(50000/64)
#define LDA1 104      // A-lds / Bs stride (shorts): 208B rows
#define LDW 40        // W-stage stride (shorts): 80B rows, 16B-aligned

typedef float f32x4 __attribute__((ext_vector_type(4)));
typedef short s16x8 __attribute__((ext_vector_type(8)));
typedef unsigned short ushort;

__device__ __forceinline__ ushort bf16_rne(float f) {
    unsigned u = __float_as_uint(f);
    u += 0x7fffu + ((u >> 16) & 1u);
    return (ushort)(u >> 16);
}
__device__ __forceinline__ float bf16_f(ushort h) {
    return __uint_as_float(((unsigned)h) << 16);
}

// ---------------- CSR build ----------------
__global__ __launch_bounds__(256) void k_count(const int* __restrict__ rows,
                                               const int* __restrict__ cols,
                                               int* __restrict__ cnt) {
    int i = blockIdx.x * 256 + threadIdx.x;
    if (i >= N_EDGES / 2) return;
    int2 r2 = ((const int2*)rows)[i];
    int2 c2 = ((const int2*)cols)[i];
    if (r2.x != c2.x) atomicAdd(&cnt[r2.x], 1);
    if (r2.y != c2.y) atomicAdd(&cnt[r2.y], 1);
}

__global__ __launch_bounds__(256) void k_scan1(const int* __restrict__ cnt,
                                               int* __restrict__ rowptr,
                                               int* __restrict__ bsum) {
    __shared__ int s[256];
    int t = threadIdx.x, e = blockIdx.x * 256 + t;
    int v = (e < N_NODES) ? cnt[e] : 0;
    s[t] = v;
    __syncthreads();
    #pragma unroll
    for (int off = 1; off < 256; off <<= 1) {
        int nv = (t >= off) ? s[t - off] : 0;
        __syncthreads();
        s[t] += nv;
        __syncthreads();
    }
    if (e < N_NODES) rowptr[e] = s[t] - v;
    if (t == 255) bsum[blockIdx.x] = s[255];
}

__global__ __launch_bounds__(256) void k_scan2(int* __restrict__ bsum,
                                               int* __restrict__ boff,
                                               int* __restrict__ rowptr) {
    __shared__ int s[256];
    int t = threadIdx.x;
    int v = (t < SCAN_NB) ? bsum[t] : 0;
    s[t] = v;
    __syncthreads();
    #pragma unroll
    for (int off = 1; off < 256; off <<= 1) {
        int nv = (t >= off) ? s[t - off] : 0;
        __syncthreads();
        s[t] += nv;
        __syncthreads();
    }
    if (t < SCAN_NB) boff[t] = s[t] - v;
    if (t == 255) rowptr[N_NODES] = s[255];
}

__global__ __launch_bounds__(256) void k_scan3(const int* __restrict__ boff,
                                               const int* __restrict__ cnt,
                                               int* __restrict__ rowptr,
                                               int* __restrict__ cursor,
                                               float* __restrict__ dinv) {
    int e = blockIdx.x * 256 + threadIdx.x;
    if (e >= N_NODES) return;
    int r = rowptr[e] + boff[blockIdx.x];
    rowptr[e] = r;
    cursor[e] = r;
    dinv[e] = rsqrtf((float)cnt[e] + 1.0f);
}

// single-pass scatter; packs (col, dinv[col])
__global__ __launch_bounds__(256) void k_scatter(const int* __restrict__ rows,
                                                 const int* __restrict__ cols,
                                                 const float* __restrict__ dinv,
                                                 int* __restrict__ cursor,
                                                 int2* __restrict__ cw) {
    int e = blockIdx.x * 256 + threadIdx.x;
    if (e >= N_EDGES) return;
    int r = rows[e], c = cols[e];
    if (r == c) return;  // set_diag zeroes pre-existing diagonal entries
    int p = atomicAdd(&cursor[r], 1);
    long long v = ((long long)(unsigned)__float_as_int(dinv[c]) << 32) | (unsigned)c;
    __builtin_nontemporal_store(v, (long long*)&cw[p]);
}

// ---------------- weight transpose + bf16 round (hi only) ----------------
__global__ __launch_bounds__(256) void k_wsplit(const float* __restrict__ src,
                                                ushort* __restrict__ dh,
                                                int K, int N, int total) {
    int idx = blockIdx.x * 256 + threadIdx.x;
    if (idx >= total) return;
    int kn = K * N;
    int g = idx / kn, rem = idx - g * kn;
    int k = rem / N, n = rem - k * N;
    dh[g * kn + n * K + k] = bf16_rne(src[idx]);
}

// ---------------- row-normalize features -> bf16 ----------------
__global__ __launch_bounds__(256) void k_norm(const float* __restrict__ feat,
                                              ushort* __restrict__ x) {
    int wid = (blockIdx.x * 256 + threadIdx.x) >> 6;
    int lane = threadIdx.x & 63;
    if (wid >= N_NODES) return;
    const float* fr = feat + (size_t)wid * IN_F;
    float v0 = (lane < IN_F) ? fr[lane] : 0.0f;
    float v1 = (lane < IN_F - 64) ? fr[64 + lane] : 0.0f;
    float ss = v0 * v0 + v1 * v1;
    #pragma unroll
    for (int o = 32; o; o >>= 1) ss += __shfl_xor(ss, o, 64);
    float inv = 1.0f / fmaxf(sqrtf(ss), 1e-12f);
    ushort* xr = x + (size_t)wid * IN_F;
    if (lane < IN_F) xr[lane] = bf16_rne(v0 * inv);
    if (lane < IN_F - 64) xr[64 + lane] = bf16_rne(v1 * inv);
}

// ---------------- CSR SpMM: bf16 gather, fp32 accum, bf16 store; unroll 4 ----------------
__global__ __launch_bounds__(256) void k_spmm_csr(const int* __restrict__ rowptr,
                                                  const int2* __restrict__ cw,
                                                  const float* __restrict__ dinv,
                                                  const ushort* __restrict__ x,
                                                  ushort* __restrict__ y) {
    int g = (blockIdx.x * 256 + threadIdx.x) >> 5;
    if (g >= N_NODES) return;
    int l = threadIdx.x & 31;  // lane handles feats l, l+32, l+64
    float dr = dinv[g];
    const ushort* xg = x + (size_t)g * IN_F;
    float s0 = bf16_f(xg[l]), s1 = bf16_f(xg[l + 32]), s2 = bf16_f(xg[l + 64]);
    float a0 = 0.f, a1 = 0.f, a2 = 0.f;
    float b0 = 0.f, b1 = 0.f, b2 = 0.f;
    float c0 = 0.f, c1 = 0.f, c2 = 0.f;
    float d0 = 0.f, d1 = 0.f, d2 = 0.f;
    int k = rowptr[g], e = rowptr[g + 1];
    for (; k + 3 < e; k += 4) {  // 4 independent gather chains in flight
        int2 p0 = cw[k], p1 = cw[k + 1], p2 = cw[k + 2], p3 = cw[k + 3];
        const ushort* x0 = x + (size_t)p0.x * IN_F;
        const ushort* x1 = x + (size_t)p1.x * IN_F;
        const ushort* x2 = x + (size_t)p2.x * IN_F;
        const ushort* x3 = x + (size_t)p3.x * IN_F;
        float w0 = __int_as_float(p0.y), w1 = __int_as_float(p1.y);
        float w2 = __int_as_float(p2.y), w3 = __int_as_float(p3.y);
        a0 += bf16_f(x0[l]) * w0; a1 += bf16_f(x0[l + 32]) * w0; a2 += bf16_f(x0[l + 64]) * w0;
        b0 += bf16_f(x1[l]) * w1; b1 += bf16_f(x1[l + 32]) * w1; b2 += bf16_f(x1[l + 64]) * w1;
        c0 += bf16_f(x2[l]) * w2; c1 += bf16_f(x2[l + 32]) * w2; c2 += bf16_f(x2[l + 64]) * w2;
        d0 += bf16_f(x3[l]) * w3; d1 += bf16_f(x3[l + 32]) * w3; d2 += bf16_f(x3[l + 64]) * w3;
    }
    for (; k < e; ++k) {
        int2 p0 = cw[k];
        float w0 = __int_as_float(p0.y);
        const ushort* x0 = x + (size_t)p0.x * IN_F;
        a0 += bf16_f(x0[l]) * w0; a1 += bf16_f(x0[l + 32]) * w0; a2 += bf16_f(x0[l + 64]) * w0;
    }
    ushort* yr = y + (size_t)g * IN_F;
    yr[l]      = bf16_rne(dr * ((a0 + b0) + (c0 + d0) + dr * s0));
    yr[l + 32] = bf16_rne(dr * ((a1 + b1) + (c1 + d1) + dr * s1));
    yr[l + 64] = bf16_rne(dr * ((a2 + b2) + (c2 + d2) + dr * s2));
}

// ---------------- MEGA v8: 2-deep W prefetch, Bs reg-prefetch, LDS-transposed epilogue ----------------
// out = relu( sum_i relu(h_i @ WsT_i + bs_i) @ WfT_i + bf ), written once.
__global__ __launch_bounds__(512, 4) void k_mega(const ushort* __restrict__ h0,
                                                 const ushort* __restrict__ h1,
                                                 const ushort* __restrict__ h2,
                                                 const ushort* __restrict__ h3,
                                                 const ushort* __restrict__ WsT,
                                                 const float* __restrict__ bs,
                                                 const ushort* __restrict__ WfT,
                                                 const float* __restrict__ bf,
                                                 float* __restrict__ out) {
    __shared__ ushort SM[36864];        // 73.7 KB total
    ushort* nsH = SM;                   // [64][256] swizzled (16384)
    ushort* Wb0 = SM + 16384;           // 10240 (phase-1 Bs overlay)
    ushort* Wb1 = SM + 26624;           // 10240 (phase-1 Ah overlay)
    ushort* Bs = Wb0;                   // [64][LDA1] = 6656 <= 10240
    ushort* Ah = Wb1;                   // [64][LDA1] = 6656 <= 10240
    float* T = (float*)SM;              // epilogue scratch [32][260] f32 (33.3 KB)

    int m0 = blockIdx.x * BM;
    int tid = threadIdx.x;
    int lane = tid & 63, w = tid >> 6;
    int rsel = lane & 15, g = lane >> 4, ksel = g * 8;
    int crow = g * 4, ccol = rsel;
    int rw0 = (w & 3) * 16;   // phase-1 row-fragment base
    int cwb = (w >> 2) * 32;  // phase-1 col base within each 64-col chunk

    // staging index helpers
    int sr0 = tid / 12, sj0 = tid - sr0 * 12;          // item 0 of [64][12]
    int f1 = tid + 512;
    int sr1 = f1 / 12, sj1 = f1 - sr1 * 12;            // item 1 (tid < 256)
    int wr_ = tid >> 2, wj_ = tid & 3;                 // W items: [256][4]

    f32x4 acc[4][2] = {};  // persistent: rows rf*16.., cols w*32+cf*16..

    for (int hop = 0; hop < N_NIE; ++hop) {
        const ushort* A = (hop == 0) ? h0 : (hop == 1) ? h1 : (hop == 2) ? h2 : h3;
        const ushort* wsT = WsT + hop * IN_F * H_F;  // [n=256][k=96] bf16
        const ushort* wfT = WfT + hop * H_F * H_F;   // [n=256][k=256] bf16
        const float* bsi = bs + hop * H_F;

        // ---- stage A (bf16, plain copy) to LDS: 768 s16x8 items [64][12] ----
        {
            int gm = m0 + sr0;
            s16x8 v = {0, 0, 0, 0, 0, 0, 0, 0};
            if (gm < N_NODES) v = *(const s16x8*)&A[(size_t)gm * IN_F + sj0 * 8];
            *(s16x8*)&Ah[sr0 * LDA1 + sj0 * 8] = v;
            if (tid < 256) {
                int gm1 = m0 + sr1;
                s16x8 v1 = {0, 0, 0, 0, 0, 0, 0, 0};
                if (gm1 < N_NODES) v1 = *(const s16x8*)&A[(size_t)gm1 * IN_F + sj1 * 8];
                *(s16x8*)&Ah[sr1 * LDA1 + sj1 * 8] = v1;
            }
        }
        // ---- phase 1: nsH = relu(A @ WsT + bs), 4 chunks of 64 cols; Bs reg-prefetch ----
        s16x8 breg0 = *(const s16x8*)&wsT[(size_t)sr0 * IN_F + sj0 * 8];
        s16x8 breg1 = {0, 0, 0, 0, 0, 0, 0, 0};
        if (tid < 256) breg1 = *(const s16x8*)&wsT[(size_t)sr1 * IN_F + sj1 * 8];
        s16x8 wrA[2], wrB[2];
        #pragma unroll
        for (int c = 0; c < 4; ++c) {
            __syncthreads();  // Bs reads from chunk c-1 done; (c=0) hop-end drained
            *(s16x8*)&Bs[sr0 * LDA1 + sj0 * 8] = breg0;
            if (tid < 256) *(s16x8*)&Bs[sr1 * LDA1 + sj1 * 8] = breg1;
            __syncthreads();  // Bs (+A at c=0) visible
            if (c < 3) {  // prefetch next Bs chunk under MFMA
                const ushort* src = wsT + (size_t)(c + 1) * 64 * IN_F;
                breg0 = *(const s16x8*)&src[(size_t)sr0 * IN_F + sj0 * 8];
                if (tid < 256) breg1 = *(const s16x8*)&src[(size_t)sr1 * IN_F + sj1 * 8];
            } else {  // prefetch phase-2 W chunks 0,1 under last MFMA
                #pragma unroll
                for (int p = 0; p < 2; ++p) {
                    wrA[p] = *(const s16x8*)&wfT[(size_t)((tid + p * 512) >> 2) * H_F +
                                                 ((tid + p * 512) & 3) * 8];
                    wrB[p] = *(const s16x8*)&wfT[(size_t)((tid + p * 512) >> 2) * H_F + 32 +
                                                 ((tid + p * 512) & 3) * 8];
                }
            }
            f32x4 ac[2] = {};
            #pragma unroll
            for (int ks = 0; ks < 3; ++ks) {
                int k0 = ks * 32 + ksel;
                s16x8 ah = *(const s16x8*)&Ah[(rw0 + rsel) * LDA1 + k0];
                s16x8 b0 = *(const s16x8*)&Bs[(cwb + rsel) * LDA1 + k0];
                s16x8 b1 = *(const s16x8*)&Bs[(cwb + 16 + rsel) * LDA1 + k0];
                ac[0] = __builtin_amdgcn_mfma_f32_16x16x32_bf16(ah, b0, ac[0], 0, 0, 0);
                ac[1] = __builtin_amdgcn_mfma_f32_16x16x32_bf16(ah, b1, ac[1], 0, 0, 0);
            }
            #pragma unroll
            for (int cf = 0; cf < 2; ++cf) {
                int col = c * 64 + cwb + cf * 16 + ccol;
                float bb = bsi[col];
                #pragma unroll
                for (int ii = 0; ii < 4; ++ii) {
                    int row = rw0 + crow + ii;
                    nsH[row * 256 + (col ^ ((row & 7) << 3))] =
                        bf16_rne(fmaxf(ac[cf][ii] + bb, 0.f));
                }
            }
        }
        __syncthreads();  // nsH complete; Bs/Ah reads drained -> W regions writable
        // ---- phase 2: acc += ns @ WfT; 2-deep prefetch, unroll-2 kc pairs ----
        #pragma unroll
        for (int kc2 = 0; kc2 < 4; ++kc2) {
            // even kc = 2*kc2 -> Wb0, regs wrA
            *(s16x8*)&Wb0[wr_ * LDW + wj_ * 8] = wrA[0];
            *(s16x8*)&Wb0[(wr_ + 128) * LDW + wj_ * 8] = wrA[1];
            __syncthreads();
            if (kc2 < 3) {
                #pragma unroll
                for (int p = 0; p < 2; ++p)
                    wrA[p] = *(const s16x8*)&wfT[(size_t)((tid + p * 512) >> 2) * H_F +
                                                 (2 * kc2 + 2) * 32 +
                                                 ((tid + p * 512) & 3) * 8];
            }
            {
                int k0 = (2 * kc2) * 32 + ksel;
                s16x8 ah4[4];
                #pragma unroll
                for (int rf = 0; rf < 4; ++rf) {
                    int row = rf * 16 + rsel;
                    ah4[rf] = *(const s16x8*)&nsH[row * 256 + (k0 ^ ((row & 7) << 3))];
                }
                #pragma unroll
                for (int cf = 0; cf < 2; ++cf) {
                    s16x8 bh = *(const s16x8*)&Wb0[(w * 32 + cf * 16 + rsel) * LDW + ksel];
                    #pragma unroll
                    for (int rf = 0; rf < 4; ++rf)
                        acc[rf][cf] = __builtin_amdgcn_mfma_f32_16x16x32_bf16(ah4[rf], bh, acc[rf][cf], 0, 0, 0);
                }
            }
            // odd kc = 2*kc2+1 -> Wb1, regs wrB
            *(s16x8*)&Wb1[wr_ * LDW + wj_ * 8] = wrB[0];
            *(s16x8*)&Wb1[(wr_ + 128) * LDW + wj_ * 8] = wrB[1];
            __syncthreads();
            if (kc2 < 3) {
                #pragma unroll
                for (int p = 0; p < 2; ++p)
                    wrB[p] = *(const s16x8*)&wfT[(size_t)((tid + p * 512) >> 2) * H_F +
                                                 (2 * kc2 + 3) * 32 +
                                                 ((tid + p * 512) & 3) * 8];
            }
            {
                int k0 = (2 * kc2 + 1) * 32 + ksel;
                s16x8 ah4[4];
                #pragma unroll
                for (int rf = 0; rf < 4; ++rf) {
                    int row = rf * 16 + rsel;
                    ah4[rf] = *(const s16x8*)&nsH[row * 256 + (k0 ^ ((row & 7) << 3))];
                }
                #pragma unroll
                for (int cf = 0; cf < 2; ++cf) {
                    s16x8 bh = *(const s16x8*)&Wb1[(w * 32 + cf * 16 + rsel) * LDW + ksel];
                    #pragma unroll
                    for (int rf = 0; rf < 4; ++rf)
                        acc[rf][cf] = __builtin_amdgcn_mfma_f32_16x16x32_bf16(ah4[rf], bh, acc[rf][cf], 0, 0, 0);
                }
            }
            __syncthreads();  // both buf reads drained before next pair's writes
        }
        // (trailing barrier of kc2 loop also protects next hop's A-stage into Wb1)
    }
    // ---- epilogue: transpose acc through LDS -> full-line float4 row stores ----
    #pragma unroll
    for (int half = 0; half < 2; ++half) {
        __syncthreads();  // prior T reads (or phase-2 LDS reads) done
        #pragma unroll
        for (int rf2 = 0; rf2 < 2; ++rf2) {
            int rf = half * 2 + rf2;
            #pragma unroll
            for (int cf = 0; cf < 2; ++cf) {
                int col = w * 32 + cf * 16 + ccol;
                #pragma unroll
                for (int ii = 0; ii < 4; ++ii)
                    T[(rf2 * 16 + crow + ii) * 260 + col] = acc[rf][cf][ii];
            }
        }
        __syncthreads();
        #pragma unroll
        for (int p = 0; p < 4; ++p) {  // 2048 float4 items: [32][64]
            int flat = tid + p * 512;
            int r = flat >> 6, jc = flat & 63;
            int gm = m0 + half * 32 + r;
            if (gm < N_NODES) {
                f32x4 v = *(f32x4*)&T[r * 260 + jc * 4];
                f32x4 bb = *(const f32x4*)&bf[jc * 4];
                f32x4 o;
                #pragma unroll
                for (int q = 0; q < 4; ++q) o[q] = fmaxf(v[q] + bb[q], 0.f);
                *(f32x4*)&out[(size_t)gm * H_F + jc * 4] = o;
            }
        }
    }
}

extern "C" void kernel_launch(void* const* d_in, const int* in_sizes, int n_in,
                              void* d_out, int out_size, void* d_ws, size_t ws_size,
                              hipStream_t stream) {
    const int* ei = (const int*)d_in[0];
    const int* rows = ei;
    const int* cols = ei + N_EDGES;
    const float* feat = (const float*)d_in[1];
    const float* Ws = (const float*)d_in[2];
    const float* bs = (const float*)d_in[3];
    const float* Wf = (const float*)d_in[4];
    const float* bf = (const float*)d_in[5];
    float* out = (float*)d_out;

    // workspace layout (~52 MB)
    ushort* h0 = (ushort*)d_ws;                    // 4 x 4,800,000 u16 (bf16 h chain)
    ushort* h1 = h0 + (size_t)N_NODES * IN_F;
    ushort* h2 = h1 + (size_t)N_NODES * IN_F;
    ushort* h3 = h2 + (size_t)N_NODES * IN_F;
    ushort* WsT = h3 + (size_t)N_NODES * IN_F;     // 98,304 u16
    ushort* WfT = WsT + N_NIE * IN_F * H_F;        // 262,144 u16
    float* dinv = (float*)(WfT + N_NIE * H_F * H_F);  // 50,000 f32
    int* rowptr = (int*)(dinv + N_NODES);          // 50,004 i32
    int* bsum = rowptr + 50004;                    // 256 i32
    int* boff = bsum + 256;                        // 256 i32
    int2* cw = (int2*)(boff + 256);                // 800,000 int2
    // CSR-build temporaries aliased into h1 (h1 written only later, by spmm)
    int* cnt = (int*)h1;
    int* cursor = cnt + N_NODES;

    hipMemsetAsync(cnt, 0, N_NODES * sizeof(int), stream);
    k_count<<<(N_EDGES / 2 + 255) / 256, 256, 0, stream>>>(rows, cols, cnt);
    k_scan1<<<SCAN_NB, 256, 0, stream>>>(cnt, rowptr, bsum);
    k_scan2<<<1, 256, 0, stream>>>(bsum, boff, rowptr);
    k_scan3<<<SCAN_NB, 256, 0, stream>>>(boff, cnt, rowptr, cursor, dinv);
    k_scatter<<<(N_EDGES + 255) / 256, 256, 0, stream>>>(rows, cols, dinv, cursor, cw);
    k_wsplit<<<(N_NIE * IN_F * H_F + 255) / 256, 256, 0, stream>>>(Ws, WsT, IN_F, H_F,
                                                                   N_NIE * IN_F * H_F);
    k_wsplit<<<(N_NIE * H_F * H_F + 255) / 256, 256, 0, stream>>>(Wf, WfT, H_F, H_F,
                                                                  N_NIE * H_F * H_F);
    k_norm<<<(N_NODES + 3) / 4, 256, 0, stream>>>(feat, h0);

    // hop chain first (h1..h3), then one fused GEMM pass
    k_spmm_csr<<<(N_NODES * 32 + 255) / 256, 256, 0, stream>>>(rowptr, cw, dinv, h0, h1);
    k_spmm_csr<<<(N_NODES * 32 + 255) / 256, 256, 0, stream>>>(rowptr, cw, dinv, h1, h2);
    k_spmm_csr<<<(N_NODES * 32 + 255) / 256, 256, 0, stream>>>(rowptr, cw, dinv, h2, h3);
    k_mega<<<NBLK, 512, 0, stream>>>(h0, h1, h2, h3, WsT, bs, WfT, bf, out);
}